// Round 10
// baseline (354.302 us; speedup 1.0000x reference)
//
#include <hip/hip_runtime.h>
#include <hip/hip_bf16.h>
#include <math.h>

// Problem constants
#define NN   2048
#define EE   32768
#define NS   32
#define NV   16
#define NB   8          // NUM_BASIS
#define DD   32
#define TT   32
#define LL   2
#define HRD  64
#define NWW  3072
#define TPE  64         // edges per k_tp tile (was 128: grid was only 768
                        // blocks = exactly 3/CU -- the grid itself capped
                        // occupancy; 64 -> 1536 blocks = 6/CU, ~4 resident)
#define PI_F 3.14159265358979323846f

// scales
#define SC_SCS (1.0f/32.0f)                 // 1/sqrt(NS*D)
#define SC_SCV 0.04419417382415922f         // 1/sqrt(NV*D)=1/sqrt(512)
#define SC_L1S 0.17677669529663687f         // 1/sqrt(32)
#define SC_L1V 0.25f                        // 1/sqrt(16)
#define SC_R1  0.25f                        // 1/sqrt(2B)
#define SC_R2  0.125f                       // 1/sqrt(HR)
#define SC_ES  0.10206207261596575f         // 1/sqrt(96)
#define SC_EV  0.125f                       // 1/sqrt(64)
#define SC_AGG 0.25f                        // 1/sqrt(16)
#define SC_L2S 0.14433756729740643f         // 1/sqrt(48)
#define SC_L2V 0.25f
#define SC_SIS 0.17677669529663687f
#define SC_SIV 0.25f

typedef __attribute__((ext_vector_type(8))) short  short8;   // 8 bf16 (4 VGPRs)
typedef __attribute__((ext_vector_type(4))) float  floatx4;  // MFMA C/D

__device__ __forceinline__ floatx4 mfma16(short8 a, short8 b, floatx4 c) {
    return __builtin_amdgcn_mfma_f32_16x16x32_bf16(a, b, c, 0, 0, 0);
}

// Parallel segmented reduction over the dst-sorted 64-edge tile.
// Segments found via single-wave ballot (tid<64 == wave 0), then
// (segment x channel) work items over all 256 threads.
__device__ __forceinline__ void seg_reduce_store(
        const float (*red)[49], const int* dst_s,
        const int* __restrict__ row_ptr, int ebase,
        int tid, int lane,
        int* segstart_s, int* wtot_s, int* nseg_s,
        float* __restrict__ outg) {
    if (tid < TPE) {   // exactly wave 0
        int seg_flag = (tid == 0) || (dst_s[tid] != dst_s[tid - 1]);
        unsigned long long m = __ballot(seg_flag != 0);
        if (lane == 0) wtot_s[0] = (int)__popcll(m);
        int seg_lidx = (int)__popcll(m & ((1ull << lane) - 1ull));
        if (seg_flag) segstart_s[seg_lidx] = tid;
    }
    __syncthreads();
    if (tid == 0) {
        nseg_s[0] = wtot_s[0];
        segstart_s[wtot_s[0]] = TPE;   // sentinel
    }
    __syncthreads();
    int nseg = nseg_s[0];
    for (int w = tid; w < nseg * 48; w += 256) {
        int seg = w / 48, c = w - seg * 48;
        int p0 = segstart_s[seg], p1 = segstart_s[seg + 1];
        int d = dst_s[p0];
        float run = 0.f;
        for (int pos = p0; pos < p1; ++pos) run += red[pos][c];
        if (row_ptr[d] >= ebase && row_ptr[d + 1] <= ebase + TPE)
            outg[d * 48 + c] = run;          // tile owns the whole CSR row
        else
            atomicAdd(&outg[d * 48 + c], run);
    }
}

// ------------------------------------------------------------- K_setup
// block 0: Householder QR; 1..64: per-type sc weights; 65..1600: W_r2 ->
// bf16 in MFMA staging order [ch][q][half][quad][tc][8]; 1601+: zero CSR.
__global__ void k_setup(const float* __restrict__ Wup, float* __restrict__ Q,
                        const float* __restrict__ emb,
                        const float* __restrict__ Wscs, const float* __restrict__ Wscv,
                        float* __restrict__ WtS, float* __restrict__ WtV,
                        const float* __restrict__ Wr2, __hip_bfloat16* __restrict__ wr2t,
                        int* __restrict__ deg, int* __restrict__ cursor) {
    int b = blockIdx.x;
    if (b == 0) {
        if (threadIdx.x != 0) return;
        double A[16][2], tau[2];
        for (int i = 0; i < 16; ++i)
            for (int j = 0; j < 2; ++j) A[i][j] = (double)Wup[i*2 + j];
        for (int j = 0; j < 2; ++j) {
            double alpha = A[j][j];
            double xn2 = 0.0;
            for (int i = j + 1; i < 16; ++i) xn2 += A[i][j]*A[i][j];
            if (xn2 == 0.0) {
                tau[j] = 0.0;
            } else {
                double nrm  = sqrt(alpha*alpha + xn2);
                double beta = (alpha >= 0.0) ? -nrm : nrm;
                tau[j] = (beta - alpha) / beta;
                double s = 1.0 / (alpha - beta);
                for (int i = j + 1; i < 16; ++i) A[i][j] *= s;
                A[j][j] = beta;
            }
            for (int k = j + 1; k < 2; ++k) {
                double w = A[j][k];
                for (int i = j + 1; i < 16; ++i) w += A[i][j]*A[i][k];
                w *= tau[j];
                A[j][k] -= w;
                for (int i = j + 1; i < 16; ++i) A[i][k] -= A[i][j]*w;
            }
        }
        double Qm[16][2];
        for (int i = 0; i < 16; ++i)
            for (int j = 0; j < 2; ++j) Qm[i][j] = (i == j) ? 1.0 : 0.0;
        for (int j = 1; j >= 0; --j) {
            for (int k = 0; k < 2; ++k) {
                double w = Qm[j][k];
                for (int i = j + 1; i < 16; ++i) w += A[i][j]*Qm[i][k];
                w *= tau[j];
                Qm[j][k] -= w;
                for (int i = j + 1; i < 16; ++i) Qm[i][k] -= A[i][j]*w;
            }
        }
        for (int i = 0; i < 16; ++i)
            for (int j = 0; j < 2; ++j) Q[i*2 + j] = (float)Qm[i][j];
    } else if (b <= 64) {
        int lt = b - 1;
        int l = lt >> 5, t = lt & 31;
        __shared__ float es[32];
        if (threadIdx.x < 32) es[threadIdx.x] = emb[t*DD + threadIdx.x];
        __syncthreads();
        const float* Ws = Wscs + (size_t)l*NS*DD*48;
        float* oS = WtS + (size_t)(l*TT + t)*NS*48;
        for (int idx = threadIdx.x; idx < NS*48; idx += 256) {
            int i = idx / 48, j = idx % 48;
            float acc = 0.f;
            for (int a = 0; a < 32; ++a) acc += es[a]*Ws[(i*DD + a)*48 + j];
            oS[idx] = acc;
        }
        const float* Wv = Wscv + (size_t)l*NV*DD*NV;
        float* oV = WtV + (size_t)(l*TT + t)*NV*NV;
        for (int idx = threadIdx.x; idx < NV*NV; idx += 256) {
            int c = idx / 16, j = idx % 16;
            float acc = 0.f;
            for (int a = 0; a < 32; ++a) acc += es[a]*Wv[(c*DD + a)*NV + j];
            oV[idx] = acc;
        }
    } else if (b <= 1600) {
        int idx = (b - 65)*256 + threadIdx.x;      // L*64*3072 total, coalesced read
        int l = idx / (HRD*NWW);
        int r = idx - l*(HRD*NWW);
        int k = r / NWW;
        int c = r - k*NWW;
        int ch = c >> 6, cc = c & 63, q = cc >> 4, tcc = cc & 15;
        int h = k >> 5, qd = (k >> 3) & 3, j = k & 7;
        size_t dst = (size_t)l*(NWW*HRD)
                   + (size_t)((ch*32 + q*8 + h*4 + qd)*128 + tcc*8 + j);
        wr2t[dst] = __float2bfloat16(Wr2[idx]);
    } else {
        int i = (b - 1601)*256 + threadIdx.x;
        if (i < NN) { deg[i] = 0; cursor[i] = 0; }
    }
}

// --------------------------------------------------------------- CSR build
__global__ void k_hist(const int* __restrict__ edst, int* __restrict__ deg) {
    int e = blockIdx.x*256 + threadIdx.x;
    atomicAdd(&deg[edst[e]], 1);
}

// Parallel scan.
__global__ void k_scan(const int* __restrict__ deg, int* __restrict__ row_ptr) {
    __shared__ int wsum[4];
    int t = threadIdx.x;
    int lane = t & 63, wave = t >> 6;
    int loc[8]; int s = 0;
    for (int k = 0; k < 8; ++k) { loc[k] = deg[t*8 + k]; s += loc[k]; }
    int inc = s;
    for (int d = 1; d < 64; d <<= 1) {
        int v = __shfl_up(inc, d);
        if (lane >= d) inc += v;
    }
    if (lane == 63) wsum[wave] = inc;
    __syncthreads();
    int woff = 0;
    for (int w = 0; w < wave; ++w) woff += wsum[w];
    int off = woff + inc - s;   // exclusive prefix for this thread
    for (int k = 0; k < 8; ++k) { row_ptr[t*8 + k] = off; off += loc[k]; }
    if (t == 255) row_ptr[2048] = off;
}

// blocks 0..127: fill pre-permuted src/dst (atomic scatter).
// blocks 128..511: ELEMENT-PARALLEL node init, coalesced writes.
__global__ void k_fill(const int* __restrict__ esrc, const int* __restrict__ edst,
                       const int* __restrict__ row_ptr, int* __restrict__ cursor,
                       int* __restrict__ srcs, int* __restrict__ dsts,
                       const float* __restrict__ xin, const float* __restrict__ Q,
                       float* __restrict__ ys0, float* __restrict__ yv0,
                       float* __restrict__ ys1, float* __restrict__ yv1,
                       float* __restrict__ xcur,
                       const float* __restrict__ Wl1v0,
                       float* __restrict__ s1, float* __restrict__ v1,
                       float* __restrict__ nsb, float* __restrict__ nsb2,
                       float* __restrict__ nvba, float* __restrict__ nvbb) {
    if (blockIdx.x < 128) {
        int e = blockIdx.x*256 + threadIdx.x;
        int d = edst[e];
        int pos = atomicAdd(&cursor[d], 1);
        int p = row_ptr[d] + pos;
        srcs[p] = esrc[e];
        dsts[p] = d;
    } else {
        int idx = (blockIdx.x - 128)*256 + threadIdx.x;   // [0, NN*48)
        int n = idx / 48, r = idx - 48*(idx / 48);
        int j = r/3, k = r - 3*j;
        float xk  = xin[n*6 + k];
        float xk3 = xin[n*6 + 3 + k];
        float yvv = Q[j*2 + 0]*xk + Q[j*2 + 1]*xk3;
        yv0[idx] = yvv;
        yv1[idx] = yvv;
        float a = 0.f;
        for (int c = 0; c < 16; ++c) {
            float yc = Q[c*2 + 0]*xk + Q[c*2 + 1]*xk3;
            a += yc*Wl1v0[c*16 + j];
        }
        v1[idx] = a*SC_L1V;
        nsb[idx] = 0.f; nsb2[idx] = 0.f;
        nvba[idx] = 0.f; nvbb[idx] = 0.f;
        if (r < 32) {
            int si = n*32 + r;
            ys0[si] = 0.f; ys1[si] = 0.f; s1[si] = 0.f;
        }
        if (r < 6) xcur[n*6 + r] = xin[n*6 + r];
    }
}

// ------------------------------ K_tp: FUSED edge geometry + radial MLP +
// radial2-MFMA + edge TP + reduce, at TPE=64 (1536 blocks = 6 blocks/CU to
// process, ~4 resident with 84 VGPR). 4 waves <-> 4 MFMA row-tiles, so the
// per-wave rt dimension vanishes (accumulators halve; less reg pressure).
//   region 0: sv  ci  0..16 -> nvba  (ea factored into epilogue)
//   region 1: vs  ci 16..32 -> nsb   (dots_t precomputed, single pass)
//   region 2: vs  ci 32..40 -> nsb2 (dots2) + vv ci 40..48 -> nvbb
// B read directly from global (wr2t L2-resident; identical per tile-pair).
__global__ void __launch_bounds__(256, 3) k_tp(
        const float* __restrict__ xcur,
        const int* __restrict__ srcs, const int* __restrict__ dsts,
        const int* __restrict__ row_ptr,
        const float* __restrict__ Wr1l,
        const __hip_bfloat16* __restrict__ wr2tl,
        const float* __restrict__ s1g, const float* __restrict__ v1g,
        float* __restrict__ nsb, float* __restrict__ nsb2,
        float* __restrict__ nvba, float* __restrict__ nvbb) {
    __shared__ __align__(16) char smem[21760];
    __shared__ float ea_s[TPE][9];
    __shared__ int   src_s[TPE];
    __shared__ int   dst_s[TPE];
    __shared__ int   segstart_s[TPE + 1];
    __shared__ int   wtot_s[1];
    __shared__ int   nseg_s[1];

    int bid = blockIdx.x;
    int region = bid % 3;
    int tile   = bid / 3;
    int ebase  = tile*TPE;
    int tid = threadIdx.x;
    int wave = tid >> 6, lane = tid & 63;
    int tc = tid & 15;
    int quad = lane >> 4;

    // prologue LDS carve: ef[16][68] @0 (4352B) | Wr1[1024] @4352 (4096B)
    // | hr[64][72] bf16 @8448 (9216B, ends 17664) -> dead before gathers.
    float* ef_lds  = (float*)smem;                       // [16][68]
    float* Wr1_lds = (float*)(smem + 4352);              // [1024]
    __hip_bfloat16* hr_lds = (__hip_bfloat16*)(smem + 8448);   // [64][72]

    if (tid < TPE) { src_s[tid] = srcs[ebase + tid]; dst_s[tid] = dsts[ebase + tid]; }
    for (int i = tid; i < 16*64; i += 256) Wr1_lds[i] = Wr1l[i];

    // ---- geometry: thread e = tid < 64
    if (tid < TPE) {
        int s = src_s[tid], d = dst_s[tid];
        for (int m = 0; m < 2; ++m) {
            float v0 = xcur[s*6 + m*3 + 0] - xcur[d*6 + m*3 + 0];
            float v1_ = xcur[s*6 + m*3 + 1] - xcur[d*6 + m*3 + 1];
            float v2 = xcur[s*6 + m*3 + 2] - xcur[d*6 + m*3 + 2];
            float len = sqrtf(v0*v0 + v1_*v1_ + v2*v2 + 1e-12f);
            float inv = 1.0f/len;
            float theta = len*(PI_F/3.0f);
            float s1v = sinf(theta), c1v = cosf(theta);
            float sc  = 2.3094010767585034f*inv;  // sqrt(2/3)*sqrt(8)
            float sp = 0.f, scur = s1v, twoc = 2.f*c1v;
            for (int bq = 0; bq < 8; ++bq) {
                ef_lds[(m*8 + bq)*68 + tid] = sc*scur;
                float sn = twoc*scur - sp;
                sp = scur; scur = sn;
            }
            float u = 2.0f*(len*(1.0f/3.0f) - 1.0f);
            float cut;
            if (u > 0.f) cut = 0.f;
            else if (u < -1.f) cut = 1.f;
            else cut = 0.5f*(1.0f - cosf(PI_F*u));
            float shs = 1.7320508075688772f*inv*cut;
            ea_s[tid][m*3 + 0] = shs*v0;
            ea_s[tid][m*3 + 1] = shs*v1_;
            ea_s[tid][m*3 + 2] = shs*v2;
        }
    }
    __syncthreads();

    // ---- radial MLP: e = tid>>2, quarter h = tid&3 (16 outs each)
    {
        int e = tid >> 2, h = tid & 3;
        float z[16];
        #pragma unroll
        for (int k = 0; k < 16; ++k) z[k] = 0.f;
        for (int f = 0; f < 16; ++f) {
            float efv = ef_lds[f*68 + e];
            #pragma unroll
            for (int k = 0; k < 16; ++k) z[k] += efv*Wr1_lds[f*64 + h*16 + k];
        }
        #pragma unroll
        for (int q8 = 0; q8 < 2; ++q8) {
            __hip_bfloat16 tmp[8];
            #pragma unroll
            for (int j = 0; j < 8; ++j) {
                float zz = z[q8*8 + j]*SC_R1;
                tmp[j] = __float2bfloat16(zz/(1.0f + expf(-zz)));
            }
            *(short8*)&hr_lds[e*72 + h*16 + q8*8] = *(short8*)tmp;
        }
    }
    __syncthreads();

    // ---- A fragments from hr_lds: 1 row-tile per wave
    const short* hrp = (const short*)(smem + 8448);
    int arow = wave*16 + tc;
    short8 a_lo = *(const short8*)(hrp + arow*72 + quad*8);
    short8 a_hi = *(const short8*)(hrp + arow*72 + 32 + quad*8);
    __syncthreads();   // hr/ef/Wr1 dead; smem reusable for gathers

    const char* wb = (const char*)wr2tl;   // staging layout: chunk ch at ch*8192
    const float sES = SC_R2*SC_ES*SC_AGG;
    const float sEV = SC_R2*SC_EV*SC_AGG;
    int e0r = wave*16 + quad*4;

    if (region == 0) {
        // ---------------- sv: ch 0..15 -> accF (ea-factored) -> nvb_a
        float (*s1t)[68] = (float(*)[68])smem;             // 8704 B
        for (int i = tid; i < TPE*32; i += 256) {
            int e = i >> 5, s = i & 31;
            s1t[s][e] = s1g[src_s[e]*32 + s];
        }
        __syncthreads();    // s1t ready; loop below is barrier-free

        float accF[4][2] = {};
        for (int ci = 0; ci < 16; ++ci) {
            const char* Bc = wb + (size_t)ci*8192 + lane*16;
            #pragma unroll
            for (int q = 0; q < 4; ++q) {
                short8 b_lo = *(const short8*)(Bc + q*2048);
                short8 b_hi = *(const short8*)(Bc + q*2048 + 1024);
                floatx4 c0 = {0.f,0.f,0.f,0.f};
                c0 = mfma16(a_lo, b_lo, c0); c0 = mfma16(a_hi, b_hi, c0);
                int m = q & 1;
                int sidx = ci*2 + (q >> 1);
                float4 sv = *(const float4*)&s1t[sidx][e0r];
                #pragma unroll
                for (int i = 0; i < 4; ++i)
                    accF[i][m] += c0[i]*((&sv.x)[i]);
            }
        }
        __syncthreads();
        float (*red)[49] = (float(*)[49])smem;
        #pragma unroll
        for (int i = 0; i < 4; ++i) {
            int pos = e0r + i;
            float f0 = accF[i][0]*sEV, f1 = accF[i][1]*sEV;
            #pragma unroll
            for (int k = 0; k < 3; ++k)
                red[pos][tc*3 + k] = f0*ea_s[pos][k] + f1*ea_s[pos][3 + k];
        }
        __syncthreads();
        seg_reduce_store((const float(*)[49])smem, dst_s, row_ptr, ebase,
                         tid, lane, segstart_s, wtot_s, nseg_s, nvba);
    } else if (region == 1) {
        // ---------------- vs part 1: ch 16..31 (u in [0,64)) -> accES -> nsb
        float (*dots_t)[68] = (float(*)[68])smem;            // 8704 B
        float (*v1t)[68]    = (float(*)[68])(smem + 8704);   // 13056 B (dies)
        for (int i = tid; i < TPE*48; i += 256) {
            int e = i/48, j = i - 48*(i/48);
            v1t[j][e] = v1g[src_s[e]*48 + j];
        }
        __syncthreads();
        for (int i = tid; i < TPE*32; i += 256) {
            int cm = i >> 6, e = i & (TPE - 1), c = cm >> 1, m = cm & 1;
            dots_t[cm][e] = v1t[c*3+0][e]*ea_s[e][m*3+0]
                          + v1t[c*3+1][e]*ea_s[e][m*3+1]
                          + v1t[c*3+2][e]*ea_s[e][m*3+2];
        }
        __syncthreads();    // dots_t ready; loop below is barrier-free

        float accES[4][3] = {};
        for (int ci = 16; ci < 32; ++ci) {
            const char* Bc = wb + (size_t)ci*8192 + lane*16;
            #pragma unroll
            for (int q = 0; q < 4; ++q) {
                short8 b_lo = *(const short8*)(Bc + q*2048);
                short8 b_hi = *(const short8*)(Bc + q*2048 + 1024);
                floatx4 c0 = {0.f,0.f,0.f,0.f};
                c0 = mfma16(a_lo, b_lo, c0); c0 = mfma16(a_hi, b_hi, c0);
                int u = ci*4 + q - 64;           // [0,64)
                int c = (u*10923) >> 16;         // u/6
                int v6 = u - 6*c;
                int m = (v6 >= 3) ? 1 : 0;
                int g = v6 - 3*m;
                float4 dv = *(const float4*)&dots_t[c*2 + m][e0r];
                #pragma unroll
                for (int i = 0; i < 4; ++i)
                    accES[i][g] += c0[i]*((&dv.x)[i]);
            }
        }
        __syncthreads();
        float (*red)[49] = (float(*)[49])smem;
        #pragma unroll
        for (int i = 0; i < 4; ++i) {
            int pos = e0r + i;
            red[pos][tc]      = accES[i][0]*sES;
            red[pos][16 + tc] = accES[i][1]*sES;
            red[pos][32 + tc] = accES[i][2]*sES;
        }
        __syncthreads();
        seg_reduce_store((const float(*)[49])smem, dst_s, row_ptr, ebase,
                         tid, lane, segstart_s, wtot_s, nseg_s, nsb);
    } else {
        // ------- vs part 2 (ch 32..39, dots2 precomputed -> nsb2)
        //         + vv (ch 40..47, ea-factored accV -> cross -> nvbb)
        float (*v1t)[68]   = (float(*)[68])smem;              // 13056 B
        float (*dots2)[68] = (float(*)[68])(smem + 13056);    // 12 rows = 3264 B
        for (int i = tid; i < TPE*48; i += 256) {
            int e = i/48, j = i - 48*(i/48);
            v1t[j][e] = v1g[src_s[e]*48 + j];
        }
        __syncthreads();
        // dots2[(c-10)*2+m][e] for c in [10,16) -- covers u in [64,96)
        for (int i = tid; i < 12*TPE; i += 256) {
            int r = i >> 6, e = i & (TPE - 1);
            int c = 10 + (r >> 1), m = r & 1;
            dots2[r][e] = v1t[c*3+0][e]*ea_s[e][m*3+0]
                        + v1t[c*3+1][e]*ea_s[e][m*3+1]
                        + v1t[c*3+2][e]*ea_s[e][m*3+2];
        }
        __syncthreads();    // dots2 ready; loop below is barrier-free

        float accES[4][3] = {};
        float accV[4][2][3] = {};
        for (int ci = 32; ci < 48; ++ci) {
            const char* Bc = wb + (size_t)ci*8192 + lane*16;
            #pragma unroll
            for (int q = 0; q < 4; ++q) {
                short8 b_lo = *(const short8*)(Bc + q*2048);
                short8 b_hi = *(const short8*)(Bc + q*2048 + 1024);
                floatx4 c0 = {0.f,0.f,0.f,0.f};
                c0 = mfma16(a_lo, b_lo, c0); c0 = mfma16(a_hi, b_hi, c0);
                if (ci < 40) {
                    int u = ci*4 + q - 64;           // [64,96)
                    int c = (u*10923) >> 16;         // u/6
                    int v6 = u - 6*c;
                    int m = (v6 >= 3) ? 1 : 0;
                    int g = v6 - 3*m;
                    int dr = (c - 10)*2 + m;
                    float4 dv = *(const float4*)&dots2[dr][e0r];
                    #pragma unroll
                    for (int i = 0; i < 4; ++i)
                        accES[i][g] += c0[i]*((&dv.x)[i]);
                } else {
                    int c = ci*2 - 80 + (q >> 1);
                    int m = q & 1;
                    float4 vx = *(const float4*)&v1t[c*3 + 0][e0r];
                    float4 vy = *(const float4*)&v1t[c*3 + 1][e0r];
                    float4 vz = *(const float4*)&v1t[c*3 + 2][e0r];
                    #pragma unroll
                    for (int i = 0; i < 4; ++i) {
                        float ww = c0[i];
                        accV[i][m][0] += ww*((&vx.x)[i]);
                        accV[i][m][1] += ww*((&vy.x)[i]);
                        accV[i][m][2] += ww*((&vz.x)[i]);
                    }
                }
            }
        }
        // epilogue 1: accES -> nsb2
        __syncthreads();           // v1t dead; red may overwrite
        float (*red)[49] = (float(*)[49])smem;
        #pragma unroll
        for (int i = 0; i < 4; ++i) {
            int pos = e0r + i;
            red[pos][tc]      = accES[i][0]*sES;
            red[pos][16 + tc] = accES[i][1]*sES;
            red[pos][32 + tc] = accES[i][2]*sES;
        }
        __syncthreads();
        seg_reduce_store((const float(*)[49])smem, dst_s, row_ptr, ebase,
                         tid, lane, segstart_s, wtot_s, nseg_s, nsb2);
        // epilogue 2: accV x ea (cross products) -> nvbb
        __syncthreads();           // all done reading red from epilogue 1
        #pragma unroll
        for (int i = 0; i < 4; ++i) {
            int pos = e0r + i;
            float u00 = accV[i][0][0], u01 = accV[i][0][1], u02 = accV[i][0][2];
            float u10 = accV[i][1][0], u11 = accV[i][1][1], u12 = accV[i][1][2];
            float a0 = ea_s[pos][0], a1 = ea_s[pos][1], a2 = ea_s[pos][2];
            float b0 = ea_s[pos][3], b1 = ea_s[pos][4], b2 = ea_s[pos][5];
            red[pos][tc*3 + 0] = (u01*a2 - u02*a1 + u11*b2 - u12*b1)*sEV;
            red[pos][tc*3 + 1] = (u02*a0 - u00*a2 + u12*b0 - u10*b2)*sEV;
            red[pos][tc*3 + 2] = (u00*a1 - u01*a0 + u10*b1 - u11*b0)*sEV;
        }
        __syncthreads();
        seg_reduce_store((const float(*)[49])smem, dst_s, row_ptr, ebase,
                         tid, lane, segstart_s, wtot_s, nseg_s, nvbb);
    }
}

// ----------------------- K6: node update (conv, gate, si, leapfrog, project)
// + FUSED next-layer lin1 + aggregator zeroing for the next k_tp.
__global__ void __launch_bounds__(256) k_nodepost(
        const float* __restrict__ ysC, const float* __restrict__ yvC,
        float* __restrict__ ysO, float* __restrict__ yvO,
        const float* __restrict__ nsb, const float* __restrict__ nsb2,
        const float* __restrict__ nvba, const float* __restrict__ nvbb,
        const int* __restrict__ nattr,
        const float* __restrict__ WtSl, const float* __restrict__ WtVl,
        const float* __restrict__ Wl2s, const float* __restrict__ Wl2v,
        const float* __restrict__ Wsis, const float* __restrict__ Wsiv,
        const float* __restrict__ harr, const float* __restrict__ mixarr, int l,
        float* __restrict__ xcur, float* __restrict__ xout2,
        const float* __restrict__ Qg,
        const float* __restrict__ Wl1sN, const float* __restrict__ Wl1vN,
        float* __restrict__ s1, float* __restrict__ v1,
        float* __restrict__ znsb, float* __restrict__ znsb2,
        float* __restrict__ znvba, float* __restrict__ znvbb,
        int do_next) {
    int wave = threadIdx.x >> 6, lane = threadIdx.x & 63;
    int n = blockIdx.x*4 + wave;
    __shared__ float ys_s[4][32], yv_s[4][48], ns_s[4][48], nv_s[4][48];
    __shared__ float cs_s[4][48], nvo_s[4][48], nsn_s[4][32];

    if (lane < 32) ys_s[wave][lane] = ysC[n*32 + lane];
    if (lane < 48) {
        yv_s[wave][lane] = yvC[n*48 + lane];
        ns_s[wave][lane] = nsb[n*48 + lane] + nsb2[n*48 + lane];
        nv_s[wave][lane] = nvba[n*48 + lane] + nvbb[n*48 + lane];
    }
    __syncthreads();
    int t = nattr[n];
    const float* WtSn = WtSl + (size_t)t*NS*48;
    const float* WtVn = WtVl + (size_t)t*NV*NV;
    float hv = harr[l];
    float h2 = hv*hv, mx = mixarr[l];

    if (lane < 48) {
        float sc = 0.f, s2 = 0.f;
        for (int i = 0; i < 32; ++i) sc += ys_s[wave][i]*WtSn[i*48 + lane];
        for (int c = 0; c < 48; ++c) s2 += ns_s[wave][c]*Wl2s[c*48 + lane];
        cs_s[wave][lane] = sc*SC_SCS + s2*SC_L2S;
    }
    __syncthreads();
    if (lane < 48) {
        int j = lane/3, k = lane - 3*j;
        float scv = 0.f, v2 = 0.f, siv = 0.f;
        for (int c = 0; c < 16; ++c) {
            float yvv = yv_s[wave][c*3 + k];
            scv += yvv*WtVn[c*16 + j];
            v2  += nv_s[wave][c*3 + k]*Wl2v[c*16 + j];
            siv += yvv*Wsiv[c*16 + j];
        }
        float convv = scv*SC_SCV + v2*SC_L2V;
        siv *= SC_SIV;
        float gate = 1.f/(1.f + expf(-cs_s[wave][32 + j]));
        float gv = gate*convv;
        float nvnew = 2.f*yv_s[wave][lane] - yvO[n*48 + lane] + h2*(mx*gv + (mx - 1.f)*siv);
        nvo_s[wave][lane] = nvnew;
        yvO[n*48 + lane] = nvnew;
    }
    if (lane < 32) {
        float sis = 0.f;
        for (int i = 0; i < 32; ++i) sis += ys_s[wave][i]*Wsis[i*32 + lane];
        sis *= SC_SIS;
        float cs = cs_s[wave][lane];
        float gs = cs/(1.f + expf(-cs));
        float nsnew = 2.f*ys_s[wave][lane] - ysO[n*32 + lane] + h2*(mx*gs + (mx - 1.f)*sis);
        nsn_s[wave][lane] = nsnew;
        ysO[n*32 + lane] = nsnew;
    }
    __syncthreads();
    if (lane < 6) {
        int i = lane/3, k = lane - 3*(lane/3);
        float acc = 0.f;
        for (int c = 0; c < 16; ++c) acc += Qg[c*2 + i]*nvo_s[wave][c*3 + k];
        xcur[n*6 + lane]  = acc;
        xout2[n*6 + lane] = acc;
    }
    if (do_next) {
        if (lane < 32) {
            float a = 0.f;
            for (int i = 0; i < 32; ++i) a += nsn_s[wave][i]*Wl1sN[i*32 + lane];
            s1[n*32 + lane] = a*SC_L1S;
        }
        if (lane < 48) {
            int j = lane/3, k = lane - 3*j;
            float a = 0.f;
            for (int c = 0; c < 16; ++c) a += nvo_s[wave][c*3 + k]*Wl1vN[c*16 + j];
            v1[n*48 + lane] = a*SC_L1V;
            znsb[n*48 + lane] = 0.f; znsb2[n*48 + lane] = 0.f;
            znvba[n*48 + lane] = 0.f; znvbb[n*48 + lane] = 0.f;
        }
    }
}

// ---------------------------------------------------------------- launch
extern "C" void kernel_launch(void* const* d_in, const int* in_sizes, int n_in,
                              void* d_out, int out_size, void* d_ws, size_t ws_size,
                              hipStream_t stream) {
    const float* x_in  = (const float*)d_in[0];
    const int*   nattr = (const int*)  d_in[2];
    const int*   esrc  = (const int*)  d_in[3];
    const int*   edst  = (const int*)  d_in[4];
    const float* emb   = (const float*)d_in[5];
    const float* Wup   = (const float*)d_in[6];
    const float* Wscs  = (const float*)d_in[7];
    const float* Wscv  = (const float*)d_in[8];
    const float* Wl1s  = (const float*)d_in[9];
    const float* Wl1v  = (const float*)d_in[10];
    const float* Wr1   = (const float*)d_in[11];
    const float* Wr2   = (const float*)d_in[12];
    const float* Wl2s  = (const float*)d_in[13];
    const float* Wl2v  = (const float*)d_in[14];
    const float* Wsis  = (const float*)d_in[15];
    const float* Wsiv  = (const float*)d_in[16];
    const float* harr  = (const float*)d_in[17];
    const float* mixar = (const float*)d_in[18];
    float* out = (float*)d_out;

    float* ws = (float*)d_ws;
    size_t off = 0;
    float* Q    = ws + off; off += 32;
    float* WtS  = ws + off; off += (size_t)LL*TT*NS*48;     // 98304
    float* WtV  = ws + off; off += (size_t)LL*TT*NV*NV;     // 16384
    float* ys0  = ws + off; off += (size_t)NN*32;
    float* yv0  = ws + off; off += (size_t)NN*48;
    float* ys1  = ws + off; off += (size_t)NN*32;
    float* yv1  = ws + off; off += (size_t)NN*48;
    float* xcur = ws + off; off += (size_t)NN*6;
    float* s1   = ws + off; off += (size_t)NN*32;
    float* v1   = ws + off; off += (size_t)NN*48;
    float* nsb  = ws + off; off += (size_t)NN*48;
    float* nsb2 = ws + off; off += (size_t)NN*48;
    float* nvba = ws + off; off += (size_t)NN*48;
    float* nvbb = ws + off; off += (size_t)NN*48;
    off = (off + 3) & ~(size_t)3;                           // 16B align
    __hip_bfloat16* wr2t = (__hip_bfloat16*)(ws + off); off += (size_t)LL*NWW*HRD/2;  // bf16
    int* deg     = (int*)(ws + off); off += NN;
    int* cursor  = (int*)(ws + off); off += NN;
    int* row_ptr = (int*)(ws + off); off += NN + 1;
    int* srcs    = (int*)(ws + off); off += EE;
    int* dsts    = (int*)(ws + off); off += EE;

    k_setup<<<1609, 256, 0, stream>>>(Wup, Q, emb, Wscs, Wscv, WtS, WtV, Wr2, wr2t,
                                      deg, cursor);
    k_hist<<<EE/256, 256, 0, stream>>>(edst, deg);
    k_scan<<<1, 256, 0, stream>>>(deg, row_ptr);
    k_fill<<<128 + NN*48/256, 256, 0, stream>>>(esrc, edst, row_ptr, cursor, srcs, dsts,
                                    x_in, Q, ys0, yv0, ys1, yv1, xcur,
                                    Wl1v, s1, v1, nsb, nsb2, nvba, nvbb);

    float* curS = ys0; float* curV = yv0;
    float* oldS = ys1; float* oldV = yv1;
    for (int l = 0; l < LL; ++l) {
        k_tp<<<3*EE/TPE, 256, 0, stream>>>(xcur, srcs, dsts, row_ptr,
                                           Wr1 + (size_t)l*16*64,
                                           wr2t + (size_t)l*NWW*HRD,
                                           s1, v1, nsb, nsb2, nvba, nvbb);
        float* xo2 = (l == LL - 1) ? out : xcur;
        int lN = (l + 1 < LL) ? (l + 1) : l;
        k_nodepost<<<NN/4, 256, 0, stream>>>(curS, curV, oldS, oldV,
                                             nsb, nsb2, nvba, nvbb, nattr,
                                             WtS + (size_t)l*TT*NS*48, WtV + (size_t)l*TT*NV*NV,
                                             Wl2s + (size_t)l*48*48, Wl2v + (size_t)l*16*16,
                                             Wsis + (size_t)l*32*32, Wsiv + (size_t)l*16*16,
                                             harr, mixar, l, xcur, xo2, Q,
                                             Wl1s + (size_t)lN*32*32, Wl1v + (size_t)lN*16*16,
                                             s1, v1, nsb, nsb2, nvba, nvbb,
                                             (l + 1 < LL) ? 1 : 0);
        float* ts = curS; curS = oldS; oldS = ts;
        float* tv = curV; curV = oldV; oldV = tv;
    }
}

// Round 11
// 351.413 us; speedup vs baseline: 1.0082x; 1.0082x over previous
//
#include <hip/hip_runtime.h>
#include <hip/hip_bf16.h>
#include <math.h>

// Problem constants
#define NN   2048
#define EE   32768
#define NS   32
#define NV   16
#define NB   8          // NUM_BASIS
#define DD   32
#define TT   32
#define LL   2
#define HRD  64
#define NWW  3072
#define TPE  64         // edges per k_tp tile (1536 blocks = 6/CU to process)
#define PI_F 3.14159265358979323846f

// scales
#define SC_SCS (1.0f/32.0f)                 // 1/sqrt(NS*D)
#define SC_SCV 0.04419417382415922f         // 1/sqrt(NV*D)=1/sqrt(512)
#define SC_L1S 0.17677669529663687f         // 1/sqrt(32)
#define SC_L1V 0.25f                        // 1/sqrt(16)
#define SC_R1  0.25f                        // 1/sqrt(2B)
#define SC_R2  0.125f                       // 1/sqrt(HR)
#define SC_ES  0.10206207261596575f         // 1/sqrt(96)
#define SC_EV  0.125f                       // 1/sqrt(64)
#define SC_AGG 0.25f                        // 1/sqrt(16)
#define SC_L2S 0.14433756729740643f         // 1/sqrt(48)
#define SC_L2V 0.25f
#define SC_SIS 0.17677669529663687f
#define SC_SIV 0.25f

typedef __attribute__((ext_vector_type(8))) short  short8;   // 8 bf16 (4 VGPRs)
typedef __attribute__((ext_vector_type(4))) float  floatx4;  // MFMA C/D

__device__ __forceinline__ floatx4 mfma16(short8 a, short8 b, floatx4 c) {
    return __builtin_amdgcn_mfma_f32_16x16x32_bf16(a, b, c, 0, 0, 0);
}

// Parallel segmented reduction over the dst-sorted 64-edge tile.
__device__ __forceinline__ void seg_reduce_store(
        const float (*red)[49], const int* dst_s,
        const int* __restrict__ row_ptr, int ebase,
        int tid, int lane,
        int* segstart_s, int* wtot_s, int* nseg_s,
        float* __restrict__ outg) {
    if (tid < TPE) {   // exactly wave 0
        int seg_flag = (tid == 0) || (dst_s[tid] != dst_s[tid - 1]);
        unsigned long long m = __ballot(seg_flag != 0);
        if (lane == 0) wtot_s[0] = (int)__popcll(m);
        int seg_lidx = (int)__popcll(m & ((1ull << lane) - 1ull));
        if (seg_flag) segstart_s[seg_lidx] = tid;
    }
    __syncthreads();
    if (tid == 0) {
        nseg_s[0] = wtot_s[0];
        segstart_s[wtot_s[0]] = TPE;   // sentinel
    }
    __syncthreads();
    int nseg = nseg_s[0];
    for (int w = tid; w < nseg * 48; w += 256) {
        int seg = w / 48, c = w - seg * 48;
        int p0 = segstart_s[seg], p1 = segstart_s[seg + 1];
        int d = dst_s[p0];
        float run = 0.f;
        for (int pos = p0; pos < p1; ++pos) run += red[pos][c];
        if (row_ptr[d] >= ebase && row_ptr[d + 1] <= ebase + TPE)
            outg[d * 48 + c] = run;          // tile owns the whole CSR row
        else
            atomicAdd(&outg[d * 48 + c], run);
    }
}

// ------------------------------------------------------------- K_setup
__global__ void k_setup(const float* __restrict__ Wup, float* __restrict__ Q,
                        const float* __restrict__ emb,
                        const float* __restrict__ Wscs, const float* __restrict__ Wscv,
                        float* __restrict__ WtS, float* __restrict__ WtV,
                        const float* __restrict__ Wr2, __hip_bfloat16* __restrict__ wr2t,
                        int* __restrict__ deg, int* __restrict__ cursor) {
    int b = blockIdx.x;
    if (b == 0) {
        if (threadIdx.x != 0) return;
        double A[16][2], tau[2];
        for (int i = 0; i < 16; ++i)
            for (int j = 0; j < 2; ++j) A[i][j] = (double)Wup[i*2 + j];
        for (int j = 0; j < 2; ++j) {
            double alpha = A[j][j];
            double xn2 = 0.0;
            for (int i = j + 1; i < 16; ++i) xn2 += A[i][j]*A[i][j];
            if (xn2 == 0.0) {
                tau[j] = 0.0;
            } else {
                double nrm  = sqrt(alpha*alpha + xn2);
                double beta = (alpha >= 0.0) ? -nrm : nrm;
                tau[j] = (beta - alpha) / beta;
                double s = 1.0 / (alpha - beta);
                for (int i = j + 1; i < 16; ++i) A[i][j] *= s;
                A[j][j] = beta;
            }
            for (int k = j + 1; k < 2; ++k) {
                double w = A[j][k];
                for (int i = j + 1; i < 16; ++i) w += A[i][j]*A[i][k];
                w *= tau[j];
                A[j][k] -= w;
                for (int i = j + 1; i < 16; ++i) A[i][k] -= A[i][j]*w;
            }
        }
        double Qm[16][2];
        for (int i = 0; i < 16; ++i)
            for (int j = 0; j < 2; ++j) Qm[i][j] = (i == j) ? 1.0 : 0.0;
        for (int j = 1; j >= 0; --j) {
            for (int k = 0; k < 2; ++k) {
                double w = Qm[j][k];
                for (int i = j + 1; i < 16; ++i) w += A[i][j]*Qm[i][k];
                w *= tau[j];
                Qm[j][k] -= w;
                for (int i = j + 1; i < 16; ++i) Qm[i][k] -= A[i][j]*w;
            }
        }
        for (int i = 0; i < 16; ++i)
            for (int j = 0; j < 2; ++j) Q[i*2 + j] = (float)Qm[i][j];
    } else if (b <= 64) {
        int lt = b - 1;
        int l = lt >> 5, t = lt & 31;
        __shared__ float es[32];
        if (threadIdx.x < 32) es[threadIdx.x] = emb[t*DD + threadIdx.x];
        __syncthreads();
        const float* Ws = Wscs + (size_t)l*NS*DD*48;
        float* oS = WtS + (size_t)(l*TT + t)*NS*48;
        for (int idx = threadIdx.x; idx < NS*48; idx += 256) {
            int i = idx / 48, j = idx % 48;
            float acc = 0.f;
            for (int a = 0; a < 32; ++a) acc += es[a]*Ws[(i*DD + a)*48 + j];
            oS[idx] = acc;
        }
        const float* Wv = Wscv + (size_t)l*NV*DD*NV;
        float* oV = WtV + (size_t)(l*TT + t)*NV*NV;
        for (int idx = threadIdx.x; idx < NV*NV; idx += 256) {
            int c = idx / 16, j = idx % 16;
            float acc = 0.f;
            for (int a = 0; a < 32; ++a) acc += es[a]*Wv[(c*DD + a)*NV + j];
            oV[idx] = acc;
        }
    } else if (b <= 1600) {
        int idx = (b - 65)*256 + threadIdx.x;      // L*64*3072 total, coalesced read
        int l = idx / (HRD*NWW);
        int r = idx - l*(HRD*NWW);
        int k = r / NWW;
        int c = r - k*NWW;
        int ch = c >> 6, cc = c & 63, q = cc >> 4, tcc = cc & 15;
        int h = k >> 5, qd = (k >> 3) & 3, j = k & 7;
        size_t dst = (size_t)l*(NWW*HRD)
                   + (size_t)((ch*32 + q*8 + h*4 + qd)*128 + tcc*8 + j);
        wr2t[dst] = __float2bfloat16(Wr2[idx]);
    } else {
        int i = (b - 1601)*256 + threadIdx.x;
        if (i < NN) { deg[i] = 0; cursor[i] = 0; }
    }
}

// --------------------------------------------------------------- CSR build
__global__ void k_hist(const int* __restrict__ edst, int* __restrict__ deg) {
    int e = blockIdx.x*256 + threadIdx.x;
    atomicAdd(&deg[edst[e]], 1);
}

__global__ void k_scan(const int* __restrict__ deg, int* __restrict__ row_ptr) {
    __shared__ int wsum[4];
    int t = threadIdx.x;
    int lane = t & 63, wave = t >> 6;
    int loc[8]; int s = 0;
    for (int k = 0; k < 8; ++k) { loc[k] = deg[t*8 + k]; s += loc[k]; }
    int inc = s;
    for (int d = 1; d < 64; d <<= 1) {
        int v = __shfl_up(inc, d);
        if (lane >= d) inc += v;
    }
    if (lane == 63) wsum[wave] = inc;
    __syncthreads();
    int woff = 0;
    for (int w = 0; w < wave; ++w) woff += wsum[w];
    int off = woff + inc - s;   // exclusive prefix for this thread
    for (int k = 0; k < 8; ++k) { row_ptr[t*8 + k] = off; off += loc[k]; }
    if (t == 255) row_ptr[2048] = off;
}

// blocks 0..127: fill pre-permuted src/dst; 128..511: element-parallel init.
__global__ void k_fill(const int* __restrict__ esrc, const int* __restrict__ edst,
                       const int* __restrict__ row_ptr, int* __restrict__ cursor,
                       int* __restrict__ srcs, int* __restrict__ dsts,
                       const float* __restrict__ xin, const float* __restrict__ Q,
                       float* __restrict__ ys0, float* __restrict__ yv0,
                       float* __restrict__ ys1, float* __restrict__ yv1,
                       float* __restrict__ xcur,
                       const float* __restrict__ Wl1v0,
                       float* __restrict__ s1, float* __restrict__ v1,
                       float* __restrict__ nsb, float* __restrict__ nsb2,
                       float* __restrict__ nvba, float* __restrict__ nvbb) {
    if (blockIdx.x < 128) {
        int e = blockIdx.x*256 + threadIdx.x;
        int d = edst[e];
        int pos = atomicAdd(&cursor[d], 1);
        int p = row_ptr[d] + pos;
        srcs[p] = esrc[e];
        dsts[p] = d;
    } else {
        int idx = (blockIdx.x - 128)*256 + threadIdx.x;   // [0, NN*48)
        int n = idx / 48, r = idx - 48*(idx / 48);
        int j = r/3, k = r - 3*j;
        float xk  = xin[n*6 + k];
        float xk3 = xin[n*6 + 3 + k];
        float yvv = Q[j*2 + 0]*xk + Q[j*2 + 1]*xk3;
        yv0[idx] = yvv;
        yv1[idx] = yvv;
        float a = 0.f;
        for (int c = 0; c < 16; ++c) {
            float yc = Q[c*2 + 0]*xk + Q[c*2 + 1]*xk3;
            a += yc*Wl1v0[c*16 + j];
        }
        v1[idx] = a*SC_L1V;
        nsb[idx] = 0.f; nsb2[idx] = 0.f;
        nvba[idx] = 0.f; nvbb[idx] = 0.f;
        if (r < 32) {
            int si = n*32 + r;
            ys0[si] = 0.f; ys1[si] = 0.f; s1[si] = 0.f;
        }
        if (r < 6) xcur[n*6 + r] = xin[n*6 + r];
    }
}

// ------------------------------ K_tp: FUSED edge geometry + radial MLP +
// radial2-MFMA + edge TP + reduce, TPE=64 (1536 blocks). All three chunk
// loops are NOW EXPLICITLY #pragma unroll: R10's regression was the
// compiler NOT unrolling them at TPE=64, leaving the accumulator index g
// (computed from ci,q) runtime-dynamic -> accES/accV spilled to scratch
// (WRITE_SIZE 132MB/dispatch, 2x slowdown). Unrolling makes u/c/m/g/dr
// compile-time so accumulators stay in registers (as they implicitly did
// at TPE=128 in R4-R9, 8MB WRITE).
__global__ void __launch_bounds__(256, 3) k_tp(
        const float* __restrict__ xcur,
        const int* __restrict__ srcs, const int* __restrict__ dsts,
        const int* __restrict__ row_ptr,
        const float* __restrict__ Wr1l,
        const __hip_bfloat16* __restrict__ wr2tl,
        const float* __restrict__ s1g, const float* __restrict__ v1g,
        float* __restrict__ nsb, float* __restrict__ nsb2,
        float* __restrict__ nvba, float* __restrict__ nvbb) {
    __shared__ __align__(16) char smem[21760];
    __shared__ float ea_s[TPE][9];
    __shared__ int   src_s[TPE];
    __shared__ int   dst_s[TPE];
    __shared__ int   segstart_s[TPE + 1];
    __shared__ int   wtot_s[1];
    __shared__ int   nseg_s[1];

    int bid = blockIdx.x;
    int region = bid % 3;
    int tile   = bid / 3;
    int ebase  = tile*TPE;
    int tid = threadIdx.x;
    int wave = tid >> 6, lane = tid & 63;
    int tc = tid & 15;
    int quad = lane >> 4;

    // prologue LDS carve: ef[16][68] @0 (4352B) | Wr1[1024] @4352 (4096B)
    // | hr[64][72] bf16 @8448 (9216B) -> dead before gathers.
    float* ef_lds  = (float*)smem;                       // [16][68]
    float* Wr1_lds = (float*)(smem + 4352);              // [1024]
    __hip_bfloat16* hr_lds = (__hip_bfloat16*)(smem + 8448);   // [64][72]

    if (tid < TPE) { src_s[tid] = srcs[ebase + tid]; dst_s[tid] = dsts[ebase + tid]; }
    for (int i = tid; i < 16*64; i += 256) Wr1_lds[i] = Wr1l[i];

    // ---- geometry: thread e = tid < 64
    if (tid < TPE) {
        int s = src_s[tid], d = dst_s[tid];
        for (int m = 0; m < 2; ++m) {
            float v0 = xcur[s*6 + m*3 + 0] - xcur[d*6 + m*3 + 0];
            float v1_ = xcur[s*6 + m*3 + 1] - xcur[d*6 + m*3 + 1];
            float v2 = xcur[s*6 + m*3 + 2] - xcur[d*6 + m*3 + 2];
            float len = sqrtf(v0*v0 + v1_*v1_ + v2*v2 + 1e-12f);
            float inv = 1.0f/len;
            float theta = len*(PI_F/3.0f);
            float s1v = sinf(theta), c1v = cosf(theta);
            float sc  = 2.3094010767585034f*inv;  // sqrt(2/3)*sqrt(8)
            float sp = 0.f, scur = s1v, twoc = 2.f*c1v;
            for (int bq = 0; bq < 8; ++bq) {
                ef_lds[(m*8 + bq)*68 + tid] = sc*scur;
                float sn = twoc*scur - sp;
                sp = scur; scur = sn;
            }
            float u = 2.0f*(len*(1.0f/3.0f) - 1.0f);
            float cut;
            if (u > 0.f) cut = 0.f;
            else if (u < -1.f) cut = 1.f;
            else cut = 0.5f*(1.0f - cosf(PI_F*u));
            float shs = 1.7320508075688772f*inv*cut;
            ea_s[tid][m*3 + 0] = shs*v0;
            ea_s[tid][m*3 + 1] = shs*v1_;
            ea_s[tid][m*3 + 2] = shs*v2;
        }
    }
    __syncthreads();

    // ---- radial MLP: e = tid>>2, quarter h = tid&3 (16 outs each)
    {
        int e = tid >> 2, h = tid & 3;
        float z[16];
        #pragma unroll
        for (int k = 0; k < 16; ++k) z[k] = 0.f;
        for (int f = 0; f < 16; ++f) {
            float efv = ef_lds[f*68 + e];
            #pragma unroll
            for (int k = 0; k < 16; ++k) z[k] += efv*Wr1_lds[f*64 + h*16 + k];
        }
        #pragma unroll
        for (int q8 = 0; q8 < 2; ++q8) {
            __hip_bfloat16 tmp[8];
            #pragma unroll
            for (int j = 0; j < 8; ++j) {
                float zz = z[q8*8 + j]*SC_R1;
                tmp[j] = __float2bfloat16(zz/(1.0f + expf(-zz)));
            }
            *(short8*)&hr_lds[e*72 + h*16 + q8*8] = *(short8*)tmp;
        }
    }
    __syncthreads();

    // ---- A fragments from hr_lds: 1 row-tile per wave
    const short* hrp = (const short*)(smem + 8448);
    int arow = wave*16 + tc;
    short8 a_lo = *(const short8*)(hrp + arow*72 + quad*8);
    short8 a_hi = *(const short8*)(hrp + arow*72 + 32 + quad*8);
    __syncthreads();   // hr/ef/Wr1 dead; smem reusable for gathers

    const char* wb = (const char*)wr2tl;   // staging layout: chunk ch at ch*8192
    const float sES = SC_R2*SC_ES*SC_AGG;
    const float sEV = SC_R2*SC_EV*SC_AGG;
    int e0r = wave*16 + quad*4;

    if (region == 0) {
        // ---------------- sv: ch 0..15 -> accF (ea-factored) -> nvb_a
        float (*s1t)[68] = (float(*)[68])smem;             // 8704 B
        for (int i = tid; i < TPE*32; i += 256) {
            int e = i >> 5, s = i & 31;
            s1t[s][e] = s1g[src_s[e]*32 + s];
        }
        __syncthreads();    // s1t ready; loop below is barrier-free

        float accF[4][2] = {};
        #pragma unroll
        for (int ci = 0; ci < 16; ++ci) {
            const char* Bc = wb + (size_t)ci*8192 + lane*16;
            #pragma unroll
            for (int q = 0; q < 4; ++q) {
                short8 b_lo = *(const short8*)(Bc + q*2048);
                short8 b_hi = *(const short8*)(Bc + q*2048 + 1024);
                floatx4 c0 = {0.f,0.f,0.f,0.f};
                c0 = mfma16(a_lo, b_lo, c0); c0 = mfma16(a_hi, b_hi, c0);
                int m = q & 1;
                int sidx = ci*2 + (q >> 1);
                float4 sv = *(const float4*)&s1t[sidx][e0r];
                #pragma unroll
                for (int i = 0; i < 4; ++i)
                    accF[i][m] += c0[i]*((&sv.x)[i]);
            }
        }
        __syncthreads();
        float (*red)[49] = (float(*)[49])smem;
        #pragma unroll
        for (int i = 0; i < 4; ++i) {
            int pos = e0r + i;
            float f0 = accF[i][0]*sEV, f1 = accF[i][1]*sEV;
            #pragma unroll
            for (int k = 0; k < 3; ++k)
                red[pos][tc*3 + k] = f0*ea_s[pos][k] + f1*ea_s[pos][3 + k];
        }
        __syncthreads();
        seg_reduce_store((const float(*)[49])smem, dst_s, row_ptr, ebase,
                         tid, lane, segstart_s, wtot_s, nseg_s, nvba);
    } else if (region == 1) {
        // ---------------- vs part 1: ch 16..31 (u in [0,64)) -> accES -> nsb
        float (*dots_t)[68] = (float(*)[68])smem;            // 8704 B
        float (*v1t)[68]    = (float(*)[68])(smem + 8704);   // 13056 B (dies)
        for (int i = tid; i < TPE*48; i += 256) {
            int e = i/48, j = i - 48*(i/48);
            v1t[j][e] = v1g[src_s[e]*48 + j];
        }
        __syncthreads();
        for (int i = tid; i < TPE*32; i += 256) {
            int cm = i >> 6, e = i & (TPE - 1), c = cm >> 1, m = cm & 1;
            dots_t[cm][e] = v1t[c*3+0][e]*ea_s[e][m*3+0]
                          + v1t[c*3+1][e]*ea_s[e][m*3+1]
                          + v1t[c*3+2][e]*ea_s[e][m*3+2];
        }
        __syncthreads();    // dots_t ready; loop below is barrier-free

        float accES[4][3] = {};
        #pragma unroll
        for (int ci = 16; ci < 32; ++ci) {
            const char* Bc = wb + (size_t)ci*8192 + lane*16;
            #pragma unroll
            for (int q = 0; q < 4; ++q) {
                short8 b_lo = *(const short8*)(Bc + q*2048);
                short8 b_hi = *(const short8*)(Bc + q*2048 + 1024);
                floatx4 c0 = {0.f,0.f,0.f,0.f};
                c0 = mfma16(a_lo, b_lo, c0); c0 = mfma16(a_hi, b_hi, c0);
                int u = ci*4 + q - 64;           // [0,64) compile-time
                int c = u/6;
                int v6 = u - 6*c;
                int m = (v6 >= 3) ? 1 : 0;
                int g = v6 - 3*m;
                float4 dv = *(const float4*)&dots_t[c*2 + m][e0r];
                #pragma unroll
                for (int i = 0; i < 4; ++i)
                    accES[i][g] += c0[i]*((&dv.x)[i]);
            }
        }
        __syncthreads();
        float (*red)[49] = (float(*)[49])smem;
        #pragma unroll
        for (int i = 0; i < 4; ++i) {
            int pos = e0r + i;
            red[pos][tc]      = accES[i][0]*sES;
            red[pos][16 + tc] = accES[i][1]*sES;
            red[pos][32 + tc] = accES[i][2]*sES;
        }
        __syncthreads();
        seg_reduce_store((const float(*)[49])smem, dst_s, row_ptr, ebase,
                         tid, lane, segstart_s, wtot_s, nseg_s, nsb);
    } else {
        // ------- vs part 2 (ch 32..39, dots2 precomputed -> nsb2)
        //         + vv (ch 40..47, ea-factored accV -> cross -> nvbb)
        float (*v1t)[68]   = (float(*)[68])smem;              // 13056 B
        float (*dots2)[68] = (float(*)[68])(smem + 13056);    // 12 rows = 3264 B
        for (int i = tid; i < TPE*48; i += 256) {
            int e = i/48, j = i - 48*(i/48);
            v1t[j][e] = v1g[src_s[e]*48 + j];
        }
        __syncthreads();
        // dots2[(c-10)*2+m][e] for c in [10,16) -- covers u in [64,96)
        for (int i = tid; i < 12*TPE; i += 256) {
            int r = i >> 6, e = i & (TPE - 1);
            int c = 10 + (r >> 1), m = r & 1;
            dots2[r][e] = v1t[c*3+0][e]*ea_s[e][m*3+0]
                        + v1t[c*3+1][e]*ea_s[e][m*3+1]
                        + v1t[c*3+2][e]*ea_s[e][m*3+2];
        }
        __syncthreads();    // dots2 ready; loop below is barrier-free

        float accES[4][3] = {};
        float accV[4][2][3] = {};
        #pragma unroll
        for (int ci = 32; ci < 48; ++ci) {
            const char* Bc = wb + (size_t)ci*8192 + lane*16;
            #pragma unroll
            for (int q = 0; q < 4; ++q) {
                short8 b_lo = *(const short8*)(Bc + q*2048);
                short8 b_hi = *(const short8*)(Bc + q*2048 + 1024);
                floatx4 c0 = {0.f,0.f,0.f,0.f};
                c0 = mfma16(a_lo, b_lo, c0); c0 = mfma16(a_hi, b_hi, c0);
                if (ci < 40) {
                    int u = ci*4 + q - 64;           // [64,96) compile-time
                    int c = u/6;
                    int v6 = u - 6*c;
                    int m = (v6 >= 3) ? 1 : 0;
                    int g = v6 - 3*m;
                    int dr = (c - 10)*2 + m;
                    float4 dv = *(const float4*)&dots2[dr][e0r];
                    #pragma unroll
                    for (int i = 0; i < 4; ++i)
                        accES[i][g] += c0[i]*((&dv.x)[i]);
                } else {
                    int c = ci*2 - 80 + (q >> 1);
                    int m = q & 1;
                    float4 vx = *(const float4*)&v1t[c*3 + 0][e0r];
                    float4 vy = *(const float4*)&v1t[c*3 + 1][e0r];
                    float4 vz = *(const float4*)&v1t[c*3 + 2][e0r];
                    #pragma unroll
                    for (int i = 0; i < 4; ++i) {
                        float ww = c0[i];
                        accV[i][m][0] += ww*((&vx.x)[i]);
                        accV[i][m][1] += ww*((&vy.x)[i]);
                        accV[i][m][2] += ww*((&vz.x)[i]);
                    }
                }
            }
        }
        // epilogue 1: accES -> nsb2
        __syncthreads();           // v1t dead; red may overwrite
        float (*red)[49] = (float(*)[49])smem;
        #pragma unroll
        for (int i = 0; i < 4; ++i) {
            int pos = e0r + i;
            red[pos][tc]      = accES[i][0]*sES;
            red[pos][16 + tc] = accES[i][1]*sES;
            red[pos][32 + tc] = accES[i][2]*sES;
        }
        __syncthreads();
        seg_reduce_store((const float(*)[49])smem, dst_s, row_ptr, ebase,
                         tid, lane, segstart_s, wtot_s, nseg_s, nsb2);
        // epilogue 2: accV x ea (cross products) -> nvbb
        __syncthreads();           // all done reading red from epilogue 1
        #pragma unroll
        for (int i = 0; i < 4; ++i) {
            int pos = e0r + i;
            float u00 = accV[i][0][0], u01 = accV[i][0][1], u02 = accV[i][0][2];
            float u10 = accV[i][1][0], u11 = accV[i][1][1], u12 = accV[i][1][2];
            float a0 = ea_s[pos][0], a1 = ea_s[pos][1], a2 = ea_s[pos][2];
            float b0 = ea_s[pos][3], b1 = ea_s[pos][4], b2 = ea_s[pos][5];
            red[pos][tc*3 + 0] = (u01*a2 - u02*a1 + u11*b2 - u12*b1)*sEV;
            red[pos][tc*3 + 1] = (u02*a0 - u00*a2 + u12*b0 - u10*b2)*sEV;
            red[pos][tc*3 + 2] = (u00*a1 - u01*a0 + u10*b1 - u11*b0)*sEV;
        }
        __syncthreads();
        seg_reduce_store((const float(*)[49])smem, dst_s, row_ptr, ebase,
                         tid, lane, segstart_s, wtot_s, nseg_s, nvbb);
    }
}

// ----------------------- K6: node update (conv, gate, si, leapfrog, project)
// + FUSED next-layer lin1 + aggregator zeroing for the next k_tp.
__global__ void __launch_bounds__(256) k_nodepost(
        const float* __restrict__ ysC, const float* __restrict__ yvC,
        float* __restrict__ ysO, float* __restrict__ yvO,
        const float* __restrict__ nsb, const float* __restrict__ nsb2,
        const float* __restrict__ nvba, const float* __restrict__ nvbb,
        const int* __restrict__ nattr,
        const float* __restrict__ WtSl, const float* __restrict__ WtVl,
        const float* __restrict__ Wl2s, const float* __restrict__ Wl2v,
        const float* __restrict__ Wsis, const float* __restrict__ Wsiv,
        const float* __restrict__ harr, const float* __restrict__ mixarr, int l,
        float* __restrict__ xcur, float* __restrict__ xout2,
        const float* __restrict__ Qg,
        const float* __restrict__ Wl1sN, const float* __restrict__ Wl1vN,
        float* __restrict__ s1, float* __restrict__ v1,
        float* __restrict__ znsb, float* __restrict__ znsb2,
        float* __restrict__ znvba, float* __restrict__ znvbb,
        int do_next) {
    int wave = threadIdx.x >> 6, lane = threadIdx.x & 63;
    int n = blockIdx.x*4 + wave;
    __shared__ float ys_s[4][32], yv_s[4][48], ns_s[4][48], nv_s[4][48];
    __shared__ float cs_s[4][48], nvo_s[4][48], nsn_s[4][32];

    if (lane < 32) ys_s[wave][lane] = ysC[n*32 + lane];
    if (lane < 48) {
        yv_s[wave][lane] = yvC[n*48 + lane];
        ns_s[wave][lane] = nsb[n*48 + lane] + nsb2[n*48 + lane];
        nv_s[wave][lane] = nvba[n*48 + lane] + nvbb[n*48 + lane];
    }
    __syncthreads();
    int t = nattr[n];
    const float* WtSn = WtSl + (size_t)t*NS*48;
    const float* WtVn = WtVl + (size_t)t*NV*NV;
    float hv = harr[l];
    float h2 = hv*hv, mx = mixarr[l];

    if (lane < 48) {
        float sc = 0.f, s2 = 0.f;
        for (int i = 0; i < 32; ++i) sc += ys_s[wave][i]*WtSn[i*48 + lane];
        for (int c = 0; c < 48; ++c) s2 += ns_s[wave][c]*Wl2s[c*48 + lane];
        cs_s[wave][lane] = sc*SC_SCS + s2*SC_L2S;
    }
    __syncthreads();
    if (lane < 48) {
        int j = lane/3, k = lane - 3*j;
        float scv = 0.f, v2 = 0.f, siv = 0.f;
        for (int c = 0; c < 16; ++c) {
            float yvv = yv_s[wave][c*3 + k];
            scv += yvv*WtVn[c*16 + j];
            v2  += nv_s[wave][c*3 + k]*Wl2v[c*16 + j];
            siv += yvv*Wsiv[c*16 + j];
        }
        float convv = scv*SC_SCV + v2*SC_L2V;
        siv *= SC_SIV;
        float gate = 1.f/(1.f + expf(-cs_s[wave][32 + j]));
        float gv = gate*convv;
        float nvnew = 2.f*yv_s[wave][lane] - yvO[n*48 + lane] + h2*(mx*gv + (mx - 1.f)*siv);
        nvo_s[wave][lane] = nvnew;
        yvO[n*48 + lane] = nvnew;
    }
    if (lane < 32) {
        float sis = 0.f;
        for (int i = 0; i < 32; ++i) sis += ys_s[wave][i]*Wsis[i*32 + lane];
        sis *= SC_SIS;
        float cs = cs_s[wave][lane];
        float gs = cs/(1.f + expf(-cs));
        float nsnew = 2.f*ys_s[wave][lane] - ysO[n*32 + lane] + h2*(mx*gs + (mx - 1.f)*sis);
        nsn_s[wave][lane] = nsnew;
        ysO[n*32 + lane] = nsnew;
    }
    __syncthreads();
    if (lane < 6) {
        int i = lane/3, k = lane - 3*(lane/3);
        float acc = 0.f;
        for (int c = 0; c < 16; ++c) acc += Qg[c*2 + i]*nvo_s[wave][c*3 + k];
        xcur[n*6 + lane]  = acc;
        xout2[n*6 + lane] = acc;
    }
    if (do_next) {
        if (lane < 32) {
            float a = 0.f;
            for (int i = 0; i < 32; ++i) a += nsn_s[wave][i]*Wl1sN[i*32 + lane];
            s1[n*32 + lane] = a*SC_L1S;
        }
        if (lane < 48) {
            int j = lane/3, k = lane - 3*j;
            float a = 0.f;
            for (int c = 0; c < 16; ++c) a += nvo_s[wave][c*3 + k]*Wl1vN[c*16 + j];
            v1[n*48 + lane] = a*SC_L1V;
            znsb[n*48 + lane] = 0.f; znsb2[n*48 + lane] = 0.f;
            znvba[n*48 + lane] = 0.f; znvbb[n*48 + lane] = 0.f;
        }
    }
}

// ---------------------------------------------------------------- launch
extern "C" void kernel_launch(void* const* d_in, const int* in_sizes, int n_in,
                              void* d_out, int out_size, void* d_ws, size_t ws_size,
                              hipStream_t stream) {
    const float* x_in  = (const float*)d_in[0];
    const int*   nattr = (const int*)  d_in[2];
    const int*   esrc  = (const int*)  d_in[3];
    const int*   edst  = (const int*)  d_in[4];
    const float* emb   = (const float*)d_in[5];
    const float* Wup   = (const float*)d_in[6];
    const float* Wscs  = (const float*)d_in[7];
    const float* Wscv  = (const float*)d_in[8];
    const float* Wl1s  = (const float*)d_in[9];
    const float* Wl1v  = (const float*)d_in[10];
    const float* Wr1   = (const float*)d_in[11];
    const float* Wr2   = (const float*)d_in[12];
    const float* Wl2s  = (const float*)d_in[13];
    const float* Wl2v  = (const float*)d_in[14];
    const float* Wsis  = (const float*)d_in[15];
    const float* Wsiv  = (const float*)d_in[16];
    const float* harr  = (const float*)d_in[17];
    const float* mixar = (const float*)d_in[18];
    float* out = (float*)d_out;

    float* ws = (float*)d_ws;
    size_t off = 0;
    float* Q    = ws + off; off += 32;
    float* WtS  = ws + off; off += (size_t)LL*TT*NS*48;     // 98304
    float* WtV  = ws + off; off += (size_t)LL*TT*NV*NV;     // 16384
    float* ys0  = ws + off; off += (size_t)NN*32;
    float* yv0  = ws + off; off += (size_t)NN*48;
    float* ys1  = ws + off; off += (size_t)NN*32;
    float* yv1  = ws + off; off += (size_t)NN*48;
    float* xcur = ws + off; off += (size_t)NN*6;
    float* s1   = ws + off; off += (size_t)NN*32;
    float* v1   = ws + off; off += (size_t)NN*48;
    float* nsb  = ws + off; off += (size_t)NN*48;
    float* nsb2 = ws + off; off += (size_t)NN*48;
    float* nvba = ws + off; off += (size_t)NN*48;
    float* nvbb = ws + off; off += (size_t)NN*48;
    off = (off + 3) & ~(size_t)3;                           // 16B align
    __hip_bfloat16* wr2t = (__hip_bfloat16*)(ws + off); off += (size_t)LL*NWW*HRD/2;  // bf16
    int* deg     = (int*)(ws + off); off += NN;
    int* cursor  = (int*)(ws + off); off += NN;
    int* row_ptr = (int*)(ws + off); off += NN + 1;
    int* srcs    = (int*)(ws + off); off += EE;
    int* dsts    = (int*)(ws + off); off += EE;

    k_setup<<<1609, 256, 0, stream>>>(Wup, Q, emb, Wscs, Wscv, WtS, WtV, Wr2, wr2t,
                                      deg, cursor);
    k_hist<<<EE/256, 256, 0, stream>>>(edst, deg);
    k_scan<<<1, 256, 0, stream>>>(deg, row_ptr);
    k_fill<<<128 + NN*48/256, 256, 0, stream>>>(esrc, edst, row_ptr, cursor, srcs, dsts,
                                    x_in, Q, ys0, yv0, ys1, yv1, xcur,
                                    Wl1v, s1, v1, nsb, nsb2, nvba, nvbb);

    float* curS = ys0; float* curV = yv0;
    float* oldS = ys1; float* oldV = yv1;
    for (int l = 0; l < LL; ++l) {
        k_tp<<<3*EE/TPE, 256, 0, stream>>>(xcur, srcs, dsts, row_ptr,
                                           Wr1 + (size_t)l*16*64,
                                           wr2t + (size_t)l*NWW*HRD,
                                           s1, v1, nsb, nsb2, nvba, nvbb);
        float* xo2 = (l == LL - 1) ? out : xcur;
        int lN = (l + 1 < LL) ? (l + 1) : l;
        k_nodepost<<<NN/4, 256, 0, stream>>>(curS, curV, oldS, oldV,
                                             nsb, nsb2, nvba, nvbb, nattr,
                                             WtS + (size_t)l*TT*NS*48, WtV + (size_t)l*TT*NV*NV,
                                             Wl2s + (size_t)l*48*48, Wl2v + (size_t)l*16*16,
                                             Wsis + (size_t)l*32*32, Wsiv + (size_t)l*16*16,
                                             harr, mixar, l, xcur, xo2, Q,
                                             Wl1s + (size_t)lN*32*32, Wl1v + (size_t)lN*16*16,
                                             s1, v1, nsb, nsb2, nvba, nvbb,
                                             (l + 1 < LL) ? 1 : 0);
        float* ts = curS; curS = oldS; oldS = ts;
        float* tv = curV; curV = oldV; oldV = tv;
    }
}

// Round 13
// 231.602 us; speedup vs baseline: 1.5298x; 1.5173x over previous
//
#include <hip/hip_runtime.h>
#include <hip/hip_bf16.h>
#include <math.h>

// Problem constants
#define NN   2048
#define EE   32768
#define NS   32
#define NV   16
#define NB   8          // NUM_BASIS
#define DD   32
#define TT   32
#define LL   2
#define HRD  64
#define NWW  3072
#define TPE  128        // edges per k_tp tile
#define PI_F 3.14159265358979323846f

// scales
#define SC_SCS (1.0f/32.0f)                 // 1/sqrt(NS*D)
#define SC_SCV 0.04419417382415922f         // 1/sqrt(NV*D)=1/sqrt(512)
#define SC_L1S 0.17677669529663687f         // 1/sqrt(32)
#define SC_L1V 0.25f                        // 1/sqrt(16)
#define SC_R1  0.25f                        // 1/sqrt(2B)
#define SC_R2  0.125f                       // 1/sqrt(HR)
#define SC_ES  0.10206207261596575f         // 1/sqrt(96)
#define SC_EV  0.125f                       // 1/sqrt(64)
#define SC_AGG 0.25f                        // 1/sqrt(16)
#define SC_L2S 0.14433756729740643f         // 1/sqrt(48)
#define SC_L2V 0.25f
#define SC_SIS 0.17677669529663687f
#define SC_SIV 0.25f

typedef __attribute__((ext_vector_type(8))) short  short8;   // 8 bf16 (4 VGPRs)
typedef __attribute__((ext_vector_type(4))) float  floatx4;  // MFMA C/D

__device__ __forceinline__ void load_lds16(const void* g, void* l) {
    __builtin_amdgcn_global_load_lds(
        (const __attribute__((address_space(1))) unsigned int*)g,
        (__attribute__((address_space(3))) unsigned int*)l, 16, 0, 0);
}

__device__ __forceinline__ floatx4 mfma16(short8 a, short8 b, floatx4 c) {
    return __builtin_amdgcn_mfma_f32_16x16x32_bf16(a, b, c, 0, 0, 0);
}

// Parallel segmented reduction over the dst-sorted 128-edge tile.
__device__ __forceinline__ void seg_reduce_store(
        const float (*red)[49], const int* dst_s,
        const int* __restrict__ row_ptr, int ebase,
        int tid, int wave, int lane,
        int* segstart_s, int* wtot_s, int* nseg_s,
        float* __restrict__ outg) {
    int seg_flag = 0, seg_lidx = 0;
    if (tid < TPE) {   // waves 0 and 1, fully active
        seg_flag = (tid == 0) || (dst_s[tid] != dst_s[tid - 1]);
        unsigned long long m = __ballot(seg_flag != 0);
        if (lane == 0) wtot_s[wave] = (int)__popcll(m);
        seg_lidx = (int)__popcll(m & ((1ull << lane) - 1ull));
    }
    __syncthreads();
    if (seg_flag) segstart_s[seg_lidx + (wave ? wtot_s[0] : 0)] = tid;
    if (tid == 0) {
        int ns = wtot_s[0] + wtot_s[1];
        nseg_s[0] = ns;
        segstart_s[ns] = TPE;   // sentinel
    }
    __syncthreads();
    int nseg = nseg_s[0];
    for (int w = tid; w < nseg * 48; w += 256) {
        int seg = w / 48, c = w - seg * 48;
        int p0 = segstart_s[seg], p1 = segstart_s[seg + 1];
        int d = dst_s[p0];
        float run = 0.f;
        for (int pos = p0; pos < p1; ++pos) run += red[pos][c];
        if (row_ptr[d] >= ebase && row_ptr[d + 1] <= ebase + TPE)
            outg[d * 48 + c] = run;          // tile owns the whole CSR row
        else
            atomicAdd(&outg[d * 48 + c], run);
    }
}

// ------------------------------------------------------------- K_setup
__global__ void k_setup(const float* __restrict__ Wup, float* __restrict__ Q,
                        const float* __restrict__ emb,
                        const float* __restrict__ Wscs, const float* __restrict__ Wscv,
                        float* __restrict__ WtS, float* __restrict__ WtV,
                        const float* __restrict__ Wr2, __hip_bfloat16* __restrict__ wr2t,
                        int* __restrict__ deg, int* __restrict__ cursor) {
    int b = blockIdx.x;
    if (b == 0) {
        if (threadIdx.x != 0) return;
        double A[16][2], tau[2];
        for (int i = 0; i < 16; ++i)
            for (int j = 0; j < 2; ++j) A[i][j] = (double)Wup[i*2 + j];
        for (int j = 0; j < 2; ++j) {
            double alpha = A[j][j];
            double xn2 = 0.0;
            for (int i = j + 1; i < 16; ++i) xn2 += A[i][j]*A[i][j];
            if (xn2 == 0.0) {
                tau[j] = 0.0;
            } else {
                double nrm  = sqrt(alpha*alpha + xn2);
                double beta = (alpha >= 0.0) ? -nrm : nrm;
                tau[j] = (beta - alpha) / beta;
                double s = 1.0 / (alpha - beta);
                for (int i = j + 1; i < 16; ++i) A[i][j] *= s;
                A[j][j] = beta;
            }
            for (int k = j + 1; k < 2; ++k) {
                double w = A[j][k];
                for (int i = j + 1; i < 16; ++i) w += A[i][j]*A[i][k];
                w *= tau[j];
                A[j][k] -= w;
                for (int i = j + 1; i < 16; ++i) A[i][k] -= A[i][j]*w;
            }
        }
        double Qm[16][2];
        for (int i = 0; i < 16; ++i)
            for (int j = 0; j < 2; ++j) Qm[i][j] = (i == j) ? 1.0 : 0.0;
        for (int j = 1; j >= 0; --j) {
            for (int k = 0; k < 2; ++k) {
                double w = Qm[j][k];
                for (int i = j + 1; i < 16; ++i) w += A[i][j]*Qm[i][k];
                w *= tau[j];
                Qm[j][k] -= w;
                for (int i = j + 1; i < 16; ++i) Qm[i][k] -= A[i][j]*w;
            }
        }
        for (int i = 0; i < 16; ++i)
            for (int j = 0; j < 2; ++j) Q[i*2 + j] = (float)Qm[i][j];
    } else if (b <= 64) {
        int lt = b - 1;
        int l = lt >> 5, t = lt & 31;
        __shared__ float es[32];
        if (threadIdx.x < 32) es[threadIdx.x] = emb[t*DD + threadIdx.x];
        __syncthreads();
        const float* Ws = Wscs + (size_t)l*NS*DD*48;
        float* oS = WtS + (size_t)(l*TT + t)*NS*48;
        for (int idx = threadIdx.x; idx < NS*48; idx += 256) {
            int i = idx / 48, j = idx % 48;
            float acc = 0.f;
            for (int a = 0; a < 32; ++a) acc += es[a]*Ws[(i*DD + a)*48 + j];
            oS[idx] = acc;
        }
        const float* Wv = Wscv + (size_t)l*NV*DD*NV;
        float* oV = WtV + (size_t)(l*TT + t)*NV*NV;
        for (int idx = threadIdx.x; idx < NV*NV; idx += 256) {
            int c = idx / 16, j = idx % 16;
            float acc = 0.f;
            for (int a = 0; a < 32; ++a) acc += es[a]*Wv[(c*DD + a)*NV + j];
            oV[idx] = acc;
        }
    } else if (b <= 1600) {
        int idx = (b - 65)*256 + threadIdx.x;      // L*64*3072 total, coalesced read
        int l = idx / (HRD*NWW);
        int r = idx - l*(HRD*NWW);
        int k = r / NWW;
        int c = r - k*NWW;
        int ch = c >> 6, cc = c & 63, q = cc >> 4, tcc = cc & 15;
        int h = k >> 5, qd = (k >> 3) & 3, j = k & 7;
        size_t dst = (size_t)l*(NWW*HRD)
                   + (size_t)((ch*32 + q*8 + h*4 + qd)*128 + tcc*8 + j);
        wr2t[dst] = __float2bfloat16(Wr2[idx]);
    } else {
        int i = (b - 1601)*256 + threadIdx.x;
        if (i < NN) { deg[i] = 0; cursor[i] = 0; }
    }
}

// --------------------------------------------------------------- CSR build
__global__ void k_hist(const int* __restrict__ edst, int* __restrict__ deg) {
    int e = blockIdx.x*256 + threadIdx.x;
    atomicAdd(&deg[edst[e]], 1);
}

__global__ void k_scan(const int* __restrict__ deg, int* __restrict__ row_ptr) {
    __shared__ int wsum[4];
    int t = threadIdx.x;
    int lane = t & 63, wave = t >> 6;
    int loc[8]; int s = 0;
    for (int k = 0; k < 8; ++k) { loc[k] = deg[t*8 + k]; s += loc[k]; }
    int inc = s;
    for (int d = 1; d < 64; d <<= 1) {
        int v = __shfl_up(inc, d);
        if (lane >= d) inc += v;
    }
    if (lane == 63) wsum[wave] = inc;
    __syncthreads();
    int woff = 0;
    for (int w = 0; w < wave; ++w) woff += wsum[w];
    int off = woff + inc - s;   // exclusive prefix for this thread
    for (int k = 0; k < 8; ++k) { row_ptr[t*8 + k] = off; off += loc[k]; }
    if (t == 255) row_ptr[2048] = off;
}

// blocks 0..127: fill pre-permuted src/dst; 128..511: element-parallel init.
__global__ void k_fill(const int* __restrict__ esrc, const int* __restrict__ edst,
                       const int* __restrict__ row_ptr, int* __restrict__ cursor,
                       int* __restrict__ srcs, int* __restrict__ dsts,
                       const float* __restrict__ xin, const float* __restrict__ Q,
                       float* __restrict__ ys0, float* __restrict__ yv0,
                       float* __restrict__ ys1, float* __restrict__ yv1,
                       float* __restrict__ xcur,
                       const float* __restrict__ Wl1v0,
                       float* __restrict__ s1, float* __restrict__ v1,
                       float* __restrict__ nsb, float* __restrict__ nsb2,
                       float* __restrict__ nvba, float* __restrict__ nvbb) {
    if (blockIdx.x < 128) {
        int e = blockIdx.x*256 + threadIdx.x;
        int d = edst[e];
        int pos = atomicAdd(&cursor[d], 1);
        int p = row_ptr[d] + pos;
        srcs[p] = esrc[e];
        dsts[p] = d;
    } else {
        int idx = (blockIdx.x - 128)*256 + threadIdx.x;   // [0, NN*48)
        int n = idx / 48, r = idx - 48*(idx / 48);
        int j = r/3, k = r - 3*j;
        float xk  = xin[n*6 + k];
        float xk3 = xin[n*6 + 3 + k];
        float yvv = Q[j*2 + 0]*xk + Q[j*2 + 1]*xk3;
        yv0[idx] = yvv;
        yv1[idx] = yvv;
        float a = 0.f;
        for (int c = 0; c < 16; ++c) {
            float yc = Q[c*2 + 0]*xk + Q[c*2 + 1]*xk3;
            a += yc*Wl1v0[c*16 + j];
        }
        v1[idx] = a*SC_L1V;
        nsb[idx] = 0.f; nsb2[idx] = 0.f;
        nvba[idx] = 0.f; nvbb[idx] = 0.f;
        if (r < 32) {
            int si = n*32 + r;
            ys0[si] = 0.f; ys1[si] = 0.f; s1[si] = 0.f;
        }
        if (r < 6) xcur[n*6 + r] = xin[n*6 + r];
    }
}

// ------------------------------ K_tp: FUSED edge geometry + radial MLP +
// radial2-MFMA + edge TP + reduce (R9 structure) with the B LDS double-
// buffer staging RESTORED (R4 pattern, verified): one global_load_lds per
// wave per chunk replaces 8 per-wave L2 round-trips on the critical chain
// (R4 staged = 48.6us vs R5 unstaged = 52.9us for these loops).
//   region 0: sv  ci  0..16 -> nvba  (ea factored into epilogue)
//   region 1: vs  ci 16..32 -> nsb   (dots_t precomputed via 2-half v1t;
//             Bbuf reuses dead v1h space)
//   region 2: vs  ci 32..40 -> nsb2 (in-loop ea dot, R4 form) +
//             vv  ci 40..48 -> nvbb (ea-factored accV)
// Max smem: region 2 = v1t 25344 + Bbuf 16384 = 41728. Block ~48KB LDS ->
// 3 blocks/CU = exactly the 768-block grid's residency; no occupancy loss.
__global__ void __launch_bounds__(256, 3) k_tp(
        const float* __restrict__ xcur,
        const int* __restrict__ srcs, const int* __restrict__ dsts,
        const int* __restrict__ row_ptr,
        const float* __restrict__ Wr1l,
        const __hip_bfloat16* __restrict__ wr2tl,
        const float* __restrict__ s1g, const float* __restrict__ v1g,
        float* __restrict__ nsb, float* __restrict__ nsb2,
        float* __restrict__ nvba, float* __restrict__ nvbb) {
    __shared__ __align__(16) char smem[41728];
    __shared__ float ea_s[TPE][9];
    __shared__ int   src_s[TPE];
    __shared__ int   dst_s[TPE];
    __shared__ int   segstart_s[TPE + 1];
    __shared__ int   wtot_s[2];
    __shared__ int   nseg_s[1];

    int bid = blockIdx.x;
    int region = bid % 3;
    int tile   = bid / 3;
    int ebase  = tile*TPE;
    int tid = threadIdx.x;
    int wave = tid >> 6, lane = tid & 63;
    int tc = tid & 15;
    int quad = lane >> 4;

    // prologue LDS carve: ef[16][132] @0 (8448B) | Wr1[1024] @8448 (4096B)
    // | hr[128][72] bf16 @12544 (18432B, ends 30976) -> dead before gathers.
    float* ef_lds  = (float*)smem;                       // [16][132]
    float* Wr1_lds = (float*)(smem + 8448);              // [1024]
    __hip_bfloat16* hr_lds = (__hip_bfloat16*)(smem + 12544);  // [128][72]

    if (tid < TPE) { src_s[tid] = srcs[ebase + tid]; dst_s[tid] = dsts[ebase + tid]; }
    for (int i = tid; i < 16*64; i += 256) Wr1_lds[i] = Wr1l[i];

    // ---- geometry: thread e = tid < 128
    if (tid < TPE) {
        int s = src_s[tid], d = dst_s[tid];
        for (int m = 0; m < 2; ++m) {
            float v0 = xcur[s*6 + m*3 + 0] - xcur[d*6 + m*3 + 0];
            float v1_ = xcur[s*6 + m*3 + 1] - xcur[d*6 + m*3 + 1];
            float v2 = xcur[s*6 + m*3 + 2] - xcur[d*6 + m*3 + 2];
            float len = sqrtf(v0*v0 + v1_*v1_ + v2*v2 + 1e-12f);
            float inv = 1.0f/len;
            float theta = len*(PI_F/3.0f);
            float s1v = sinf(theta), c1v = cosf(theta);
            float sc  = 2.3094010767585034f*inv;  // sqrt(2/3)*sqrt(8)
            float sp = 0.f, scur = s1v, twoc = 2.f*c1v;
            for (int bq = 0; bq < 8; ++bq) {
                ef_lds[(m*8 + bq)*132 + tid] = sc*scur;
                float sn = twoc*scur - sp;
                sp = scur; scur = sn;
            }
            float u = 2.0f*(len*(1.0f/3.0f) - 1.0f);
            float cut;
            if (u > 0.f) cut = 0.f;
            else if (u < -1.f) cut = 1.f;
            else cut = 0.5f*(1.0f - cosf(PI_F*u));
            float shs = 1.7320508075688772f*inv*cut;
            ea_s[tid][m*3 + 0] = shs*v0;
            ea_s[tid][m*3 + 1] = shs*v1_;
            ea_s[tid][m*3 + 2] = shs*v2;
        }
    }
    __syncthreads();

    // ---- radial MLP: e = tid>>1, half h = tid&1 (32 outs each)
    {
        int e = tid >> 1, h = tid & 1;
        float z[32];
        #pragma unroll
        for (int k = 0; k < 32; ++k) z[k] = 0.f;
        for (int f = 0; f < 16; ++f) {
            float efv = ef_lds[f*132 + e];
            #pragma unroll
            for (int k = 0; k < 32; ++k) z[k] += efv*Wr1_lds[f*64 + h*32 + k];
        }
        #pragma unroll
        for (int q8 = 0; q8 < 4; ++q8) {
            __hip_bfloat16 tmp[8];
            #pragma unroll
            for (int j = 0; j < 8; ++j) {
                float zz = z[q8*8 + j]*SC_R1;
                tmp[j] = __float2bfloat16(zz/(1.0f + expf(-zz)));
            }
            *(short8*)&hr_lds[e*72 + h*32 + q8*8] = *(short8*)tmp;
        }
    }
    __syncthreads();

    // ---- A fragments from hr_lds: 2 row-tiles per wave
    const short* hrp = (const short*)(smem + 12544);
    short8 a_lo[2], a_hi[2];
    #pragma unroll
    for (int rt = 0; rt < 2; ++rt) {
        int row = (wave*2 + rt)*16 + tc;
        a_lo[rt] = *(const short8*)(hrp + row*72 + quad*8);
        a_hi[rt] = *(const short8*)(hrp + row*72 + 32 + quad*8);
    }
    __syncthreads();   // hr/ef/Wr1 dead; smem reusable for gathers

    const char* wb = (const char*)wr2tl;   // staging layout: chunk ch at ch*8192
    const float sES = SC_R2*SC_ES*SC_AGG;
    const float sEV = SC_R2*SC_EV*SC_AGG;

    char* Bbuf;
    if (region == 0)      Bbuf = smem + 16896;
    else if (region == 1) Bbuf = smem + 16896;
    else                  Bbuf = smem + 25344;

    auto stage = [&](int ch, int b) {
        const char* g = wb + (size_t)ch*8192 + wave*2048 + lane*16;
        char* l = Bbuf + b*8192 + wave*2048;       // wave-uniform lds base
        load_lds16(g, l);
        load_lds16(g + 1024, l + 1024);
    };

    if (region == 0) {
        // ---------------- sv: ch 0..15 -> accF (ea-factored) -> nvb_a
        float (*s1t)[132] = (float(*)[132])smem;            // 16896 B
        for (int i = tid; i < TPE*32; i += 256) {
            int e = i >> 5, s = i & 31;
            s1t[s][e] = s1g[src_s[e]*32 + s];
        }
        stage(0, 0);

        float accF[2][4][2] = {};
        for (int ci = 0; ci < 16; ++ci) {
            __syncthreads();                       // drains stage(ci) + gather
            if (ci + 1 < 16) stage(ci + 1, (ci + 1) & 1);
            const char* B = Bbuf + (ci & 1)*8192;
            #pragma unroll
            for (int q = 0; q < 4; ++q) {
                short8 b_lo = *(const short8*)(B + (q*8 + quad)*256 + tc*16);
                short8 b_hi = *(const short8*)(B + (q*8 + 4 + quad)*256 + tc*16);
                floatx4 c0 = {0.f,0.f,0.f,0.f}, c1 = {0.f,0.f,0.f,0.f};
                c0 = mfma16(a_lo[0], b_lo, c0); c0 = mfma16(a_hi[0], b_hi, c0);
                c1 = mfma16(a_lo[1], b_lo, c1); c1 = mfma16(a_hi[1], b_hi, c1);
                int m = q & 1;
                int sidx = ci*2 + (q >> 1);
                #pragma unroll
                for (int rt = 0; rt < 2; ++rt) {
                    int e0r = (wave*2 + rt)*16 + quad*4;
                    float4 sv = *(const float4*)&s1t[sidx][e0r];
                    floatx4 cc = rt ? c1 : c0;
                    #pragma unroll
                    for (int i = 0; i < 4; ++i)
                        accF[rt][i][m] += cc[i]*((&sv.x)[i]);
                }
            }
        }
        __syncthreads();
        float (*red)[49] = (float(*)[49])smem;
        #pragma unroll
        for (int rt = 0; rt < 2; ++rt) {
            int e0r = (wave*2 + rt)*16 + quad*4;
            #pragma unroll
            for (int i = 0; i < 4; ++i) {
                int pos = e0r + i;
                float f0 = accF[rt][i][0]*sEV, f1 = accF[rt][i][1]*sEV;
                #pragma unroll
                for (int k = 0; k < 3; ++k)
                    red[pos][tc*3 + k] = f0*ea_s[pos][k] + f1*ea_s[pos][3 + k];
            }
        }
        __syncthreads();
        seg_reduce_store((const float(*)[49])smem, dst_s, row_ptr, ebase,
                         tid, wave, lane, segstart_s, wtot_s, nseg_s, nvba);
    } else if (region == 1) {
        // ---------------- vs part 1: ch 16..31 -> accES -> nsb
        // v1t staged in two 24-row halves; Bbuf reuses dead v1h space.
        float (*dots_t)[132] = (float(*)[132])smem;           // 16896 B
        float (*v1h)[132]    = (float(*)[132])(smem + 16896); // 24 rows, dies
        for (int half = 0; half < 2; ++half) {
            int jbase = half*24;
            for (int i = tid; i < TPE*24; i += 256) {
                int e = i/24, j = i - 24*(i/24);
                v1h[j][e] = v1g[src_s[e]*48 + jbase + j];
            }
            __syncthreads();
            for (int i = tid; i < TPE*16; i += 256) {
                int cm = i >> 7, e = i & (TPE - 1);
                int c = cm >> 1, m = cm & 1;
                dots_t[half*16 + cm][e] = v1h[c*3+0][e]*ea_s[e][m*3+0]
                                        + v1h[c*3+1][e]*ea_s[e][m*3+1]
                                        + v1h[c*3+2][e]*ea_s[e][m*3+2];
            }
            __syncthreads();   // v1h dead after last half; Bbuf may overwrite
        }
        stage(16, 0);

        float accES[2][4][3] = {};
        for (int ci = 16; ci < 32; ++ci) {
            __syncthreads();
            if (ci + 1 < 32) stage(ci + 1, (ci + 1) & 1);
            const char* B = Bbuf + (ci & 1)*8192;
            #pragma unroll
            for (int q = 0; q < 4; ++q) {
                short8 b_lo = *(const short8*)(B + (q*8 + quad)*256 + tc*16);
                short8 b_hi = *(const short8*)(B + (q*8 + 4 + quad)*256 + tc*16);
                floatx4 c0 = {0.f,0.f,0.f,0.f}, c1 = {0.f,0.f,0.f,0.f};
                c0 = mfma16(a_lo[0], b_lo, c0); c0 = mfma16(a_hi[0], b_hi, c0);
                c1 = mfma16(a_lo[1], b_lo, c1); c1 = mfma16(a_hi[1], b_hi, c1);
                int u = ci*4 + q - 64;           // [0,64)
                int c = (u*10923) >> 16;         // u/6
                int v6 = u - 6*c;
                int m = (v6 >= 3) ? 1 : 0;
                int g = v6 - 3*m;
                #pragma unroll
                for (int rt = 0; rt < 2; ++rt) {
                    int e0r = (wave*2 + rt)*16 + quad*4;
                    float4 dv = *(const float4*)&dots_t[c*2 + m][e0r];
                    floatx4 cc = rt ? c1 : c0;
                    #pragma unroll
                    for (int i = 0; i < 4; ++i)
                        accES[rt][i][g] += cc[i]*((&dv.x)[i]);
                }
            }
        }
        __syncthreads();
        float (*red)[49] = (float(*)[49])smem;
        #pragma unroll
        for (int rt = 0; rt < 2; ++rt) {
            int e0r = (wave*2 + rt)*16 + quad*4;
            #pragma unroll
            for (int i = 0; i < 4; ++i) {
                int pos = e0r + i;
                red[pos][tc]      = accES[rt][i][0]*sES;
                red[pos][16 + tc] = accES[rt][i][1]*sES;
                red[pos][32 + tc] = accES[rt][i][2]*sES;
            }
        }
        __syncthreads();
        seg_reduce_store((const float(*)[49])smem, dst_s, row_ptr, ebase,
                         tid, wave, lane, segstart_s, wtot_s, nseg_s, nsb);
    } else {
        // ------- vs part 2 (ch 32..39, in-loop ea dot -> nsb2)
        //         + vv (ch 40..47, ea-factored accV -> cross -> nvbb)
        float (*v1t)[132] = (float(*)[132])smem;              // 25344 B
        for (int i = tid; i < TPE*48; i += 256) {
            int e = i/48, j = i%48;
            v1t[j][e] = v1g[src_s[e]*48 + j];
        }
        stage(32, 0);   // Bbuf at 25344, disjoint from v1t

        float accES[2][4][3] = {};
        float accV[2][4][2][3] = {};
        for (int ci = 32; ci < 48; ++ci) {
            __syncthreads();
            if (ci + 1 < 48) stage(ci + 1, (ci + 1) & 1);
            const char* B = Bbuf + (ci & 1)*8192;
            #pragma unroll
            for (int q = 0; q < 4; ++q) {
                short8 b_lo = *(const short8*)(B + (q*8 + quad)*256 + tc*16);
                short8 b_hi = *(const short8*)(B + (q*8 + 4 + quad)*256 + tc*16);
                floatx4 c0 = {0.f,0.f,0.f,0.f}, c1 = {0.f,0.f,0.f,0.f};
                c0 = mfma16(a_lo[0], b_lo, c0); c0 = mfma16(a_hi[0], b_hi, c0);
                c1 = mfma16(a_lo[1], b_lo, c1); c1 = mfma16(a_hi[1], b_hi, c1);
                if (ci < 40) {
                    int u = ci*4 + q - 64;           // [64,96)
                    int c = (u*10923) >> 16;         // u/6
                    int v6 = u - 6*c;
                    int m = (v6 >= 3) ? 1 : 0;
                    int g = v6 - 3*m;
                    #pragma unroll
                    for (int rt = 0; rt < 2; ++rt) {
                        int e0r = (wave*2 + rt)*16 + quad*4;
                        float4 vx = *(const float4*)&v1t[c*3 + 0][e0r];
                        float4 vy = *(const float4*)&v1t[c*3 + 1][e0r];
                        float4 vz = *(const float4*)&v1t[c*3 + 2][e0r];
                        floatx4 cc = rt ? c1 : c0;
                        #pragma unroll
                        for (int i = 0; i < 4; ++i) {
                            float dot = (&vx.x)[i]*ea_s[e0r + i][m*3 + 0]
                                      + (&vy.x)[i]*ea_s[e0r + i][m*3 + 1]
                                      + (&vz.x)[i]*ea_s[e0r + i][m*3 + 2];
                            accES[rt][i][g] += cc[i]*dot;
                        }
                    }
                } else {
                    int c = ci*2 - 80 + (q >> 1);
                    int m = q & 1;
                    #pragma unroll
                    for (int rt = 0; rt < 2; ++rt) {
                        int e0r = (wave*2 + rt)*16 + quad*4;
                        float4 vx = *(const float4*)&v1t[c*3 + 0][e0r];
                        float4 vy = *(const float4*)&v1t[c*3 + 1][e0r];
                        float4 vz = *(const float4*)&v1t[c*3 + 2][e0r];
                        floatx4 cc = rt ? c1 : c0;
                        #pragma unroll
                        for (int i = 0; i < 4; ++i) {
                            float ww = cc[i];
                            accV[rt][i][m][0] += ww*((&vx.x)[i]);
                            accV[rt][i][m][1] += ww*((&vy.x)[i]);
                            accV[rt][i][m][2] += ww*((&vz.x)[i]);
                        }
                    }
                }
            }
        }
        // epilogue 1: accES -> nsb2
        __syncthreads();           // v1t dead; red may overwrite
        float (*red)[49] = (float(*)[49])smem;
        #pragma unroll
        for (int rt = 0; rt < 2; ++rt) {
            int e0r = (wave*2 + rt)*16 + quad*4;
            #pragma unroll
            for (int i = 0; i < 4; ++i) {
                int pos = e0r + i;
                red[pos][tc]      = accES[rt][i][0]*sES;
                red[pos][16 + tc] = accES[rt][i][1]*sES;
                red[pos][32 + tc] = accES[rt][i][2]*sES;
            }
        }
        __syncthreads();
        seg_reduce_store((const float(*)[49])smem, dst_s, row_ptr, ebase,
                         tid, wave, lane, segstart_s, wtot_s, nseg_s, nsb2);
        // epilogue 2: accV x ea (cross products) -> nvbb
        __syncthreads();           // all done reading red from epilogue 1
        #pragma unroll
        for (int rt = 0; rt < 2; ++rt) {
            int e0r = (wave*2 + rt)*16 + quad*4;
            #pragma unroll
            for (int i = 0; i < 4; ++i) {
                int pos = e0r + i;
                float u00 = accV[rt][i][0][0], u01 = accV[rt][i][0][1], u02 = accV[rt][i][0][2];
                float u10 = accV[rt][i][1][0], u11 = accV[rt][i][1][1], u12 = accV[rt][i][1][2];
                float a0 = ea_s[pos][0], a1 = ea_s[pos][1], a2 = ea_s[pos][2];
                float b0 = ea_s[pos][3], b1 = ea_s[pos][4], b2 = ea_s[pos][5];
                red[pos][tc*3 + 0] = (u01*a2 - u02*a1 + u11*b2 - u12*b1)*sEV;
                red[pos][tc*3 + 1] = (u02*a0 - u00*a2 + u12*b0 - u10*b2)*sEV;
                red[pos][tc*3 + 2] = (u00*a1 - u01*a0 + u10*b1 - u11*b0)*sEV;
            }
        }
        __syncthreads();
        seg_reduce_store((const float(*)[49])smem, dst_s, row_ptr, ebase,
                         tid, wave, lane, segstart_s, wtot_s, nseg_s, nvbb);
    }
}

// ----------------------- K6: node update (conv, gate, si, leapfrog, project)
// + FUSED next-layer lin1 + aggregator zeroing for the next k_tp.
__global__ void __launch_bounds__(256) k_nodepost(
        const float* __restrict__ ysC, const float* __restrict__ yvC,
        float* __restrict__ ysO, float* __restrict__ yvO,
        const float* __restrict__ nsb, const float* __restrict__ nsb2,
        const float* __restrict__ nvba, const float* __restrict__ nvbb,
        const int* __restrict__ nattr,
        const float* __restrict__ WtSl, const float* __restrict__ WtVl,
        const float* __restrict__ Wl2s, const float* __restrict__ Wl2v,
        const float* __restrict__ Wsis, const float* __restrict__ Wsiv,
        const float* __restrict__ harr, const float* __restrict__ mixarr, int l,
        float* __restrict__ xcur, float* __restrict__ xout2,
        const float* __restrict__ Qg,
        const float* __restrict__ Wl1sN, const float* __restrict__ Wl1vN,
        float* __restrict__ s1, float* __restrict__ v1,
        float* __restrict__ znsb, float* __restrict__ znsb2,
        float* __restrict__ znvba, float* __restrict__ znvbb,
        int do_next) {
    int wave = threadIdx.x >> 6, lane = threadIdx.x & 63;
    int n = blockIdx.x*4 + wave;
    __shared__ float ys_s[4][32], yv_s[4][48], ns_s[4][48], nv_s[4][48];
    __shared__ float cs_s[4][48], nvo_s[4][48], nsn_s[4][32];

    if (lane < 32) ys_s[wave][lane] = ysC[n*32 + lane];
    if (lane < 48) {
        yv_s[wave][lane] = yvC[n*48 + lane];
        ns_s[wave][lane] = nsb[n*48 + lane] + nsb2[n*48 + lane];
        nv_s[wave][lane] = nvba[n*48 + lane] + nvbb[n*48 + lane];
    }
    __syncthreads();
    int t = nattr[n];
    const float* WtSn = WtSl + (size_t)t*NS*48;
    const float* WtVn = WtVl + (size_t)t*NV*NV;
    float hv = harr[l];
    float h2 = hv*hv, mx = mixarr[l];

    if (lane < 48) {
        float sc = 0.f, s2 = 0.f;
        for (int i = 0; i < 32; ++i) sc += ys_s[wave][i]*WtSn[i*48 + lane];
        for (int c = 0; c < 48; ++c) s2 += ns_s[wave][c]*Wl2s[c*48 + lane];
        cs_s[wave][lane] = sc*SC_SCS + s2*SC_L2S;
    }
    __syncthreads();
    if (lane < 48) {
        int j = lane/3, k = lane - 3*j;
        float scv = 0.f, v2 = 0.f, siv = 0.f;
        for (int c = 0; c < 16; ++c) {
            float yvv = yv_s[wave][c*3 + k];
            scv += yvv*WtVn[c*16 + j];
            v2  += nv_s[wave][c*3 + k]*Wl2v[c*16 + j];
            siv += yvv*Wsiv[c*16 + j];
        }
        float convv = scv*SC_SCV + v2*SC_L2V;
        siv *= SC_SIV;
        float gate = 1.f/(1.f + expf(-cs_s[wave][32 + j]));
        float gv = gate*convv;
        float nvnew = 2.f*yv_s[wave][lane] - yvO[n*48 + lane] + h2*(mx*gv + (mx - 1.f)*siv);
        nvo_s[wave][lane] = nvnew;
        yvO[n*48 + lane] = nvnew;
    }
    if (lane < 32) {
        float sis = 0.f;
        for (int i = 0; i < 32; ++i) sis += ys_s[wave][i]*Wsis[i*32 + lane];
        sis *= SC_SIS;
        float cs = cs_s[wave][lane];
        float gs = cs/(1.f + expf(-cs));
        float nsnew = 2.f*ys_s[wave][lane] - ysO[n*32 + lane] + h2*(mx*gs + (mx - 1.f)*sis);
        nsn_s[wave][lane] = nsnew;
        ysO[n*32 + lane] = nsnew;
    }
    __syncthreads();
    if (lane < 6) {
        int i = lane/3, k = lane - 3*(lane/3);
        float acc = 0.f;
        for (int c = 0; c < 16; ++c) acc += Qg[c*2 + i]*nvo_s[wave][c*3 + k];
        xcur[n*6 + lane]  = acc;
        xout2[n*6 + lane] = acc;
    }
    if (do_next) {
        if (lane < 32) {
            float a = 0.f;
            for (int i = 0; i < 32; ++i) a += nsn_s[wave][i]*Wl1sN[i*32 + lane];
            s1[n*32 + lane] = a*SC_L1S;
        }
        if (lane < 48) {
            int j = lane/3, k = lane - 3*j;
            float a = 0.f;
            for (int c = 0; c < 16; ++c) a += nvo_s[wave][c*3 + k]*Wl1vN[c*16 + j];
            v1[n*48 + lane] = a*SC_L1V;
            znsb[n*48 + lane] = 0.f; znsb2[n*48 + lane] = 0.f;
            znvba[n*48 + lane] = 0.f; znvbb[n*48 + lane] = 0.f;
        }
    }
}

// ---------------------------------------------------------------- launch
extern "C" void kernel_launch(void* const* d_in, const int* in_sizes, int n_in,
                              void* d_out, int out_size, void* d_ws, size_t ws_size,
                              hipStream_t stream) {
    const float* x_in  = (const float*)d_in[0];
    const int*   nattr = (const int*)  d_in[2];
    const int*   esrc  = (const int*)  d_in[3];
    const int*   edst  = (const int*)  d_in[4];
    const float* emb   = (const float*)d_in[5];
    const float* Wup   = (const float*)d_in[6];
    const float* Wscs  = (const float*)d_in[7];
    const float* Wscv  = (const float*)d_in[8];
    const float* Wl1s  = (const float*)d_in[9];
    const float* Wl1v  = (const float*)d_in[10];
    const float* Wr1   = (const float*)d_in[11];
    const float* Wr2   = (const float*)d_in[12];
    const float* Wl2s  = (const float*)d_in[13];
    const float* Wl2v  = (const float*)d_in[14];
    const float* Wsis  = (const float*)d_in[15];
    const float* Wsiv  = (const float*)d_in[16];
    const float* harr  = (const float*)d_in[17];
    const float* mixar = (const float*)d_in[18];
    float* out = (float*)d_out;

    float* ws = (float*)d_ws;
    size_t off = 0;
    float* Q    = ws + off; off += 32;
    float* WtS  = ws + off; off += (size_t)LL*TT*NS*48;     // 98304
    float* WtV  = ws + off; off += (size_t)LL*TT*NV*NV;     // 16384
    float* ys0  = ws + off; off += (size_t)NN*32;
    float* yv0  = ws + off; off += (size_t)NN*48;
    float* ys1  = ws + off; off += (size_t)NN*32;
    float* yv1  = ws + off; off += (size_t)NN*48;
    float* xcur = ws + off; off += (size_t)NN*6;
    float* s1   = ws + off; off += (size_t)NN*32;
    float* v1   = ws + off; off += (size_t)NN*48;
    float* nsb  = ws + off; off += (size_t)NN*48;
    float* nsb2 = ws + off; off += (size_t)NN*48;
    float* nvba = ws + off; off += (size_t)NN*48;
    float* nvbb = ws + off; off += (size_t)NN*48;
    off = (off + 3) & ~(size_t)3;                           // 16B align
    __hip_bfloat16* wr2t = (__hip_bfloat16*)(ws + off); off += (size_t)LL*NWW*HRD/2;  // bf16
    int* deg     = (int*)(ws + off); off += NN;
    int* cursor  = (int*)(ws + off); off += NN;
    int* row_ptr = (int*)(ws + off); off += NN + 1;
    int* srcs    = (int*)(ws + off); off += EE;
    int* dsts    = (int*)(ws + off); off += EE;

    k_setup<<<1609, 256, 0, stream>>>(Wup, Q, emb, Wscs, Wscv, WtS, WtV, Wr2, wr2t,
                                      deg, cursor);
    k_hist<<<EE/256, 256, 0, stream>>>(edst, deg);
    k_scan<<<1, 256, 0, stream>>>(deg, row_ptr);
    k_fill<<<128 + NN*48/256, 256, 0, stream>>>(esrc, edst, row_ptr, cursor, srcs, dsts,
                                    x_in, Q, ys0, yv0, ys1, yv1, xcur,
                                    Wl1v, s1, v1, nsb, nsb2, nvba, nvbb);

    float* curS = ys0; float* curV = yv0;
    float* oldS = ys1; float* oldV = yv1;
    for (int l = 0; l < LL; ++l) {
        k_tp<<<3*EE/TPE, 256, 0, stream>>>(xcur, srcs, dsts, row_ptr,
                                           Wr1 + (size_t)l*16*64,
                                           wr2t + (size_t)l*NWW*HRD,
                                           s1, v1, nsb, nsb2, nvba, nvbb);
        float* xo2 = (l == LL - 1) ? out : xcur;
        int lN = (l + 1 < LL) ? (l + 1) : l;
        k_nodepost<<<NN/4, 256, 0, stream>>>(curS, curV, oldS, oldV,
                                             nsb, nsb2, nvba, nvbb, nattr,
                                             WtS + (size_t)l*TT*NS*48, WtV + (size_t)l*TT*NV*NV,
                                             Wl2s + (size_t)l*48*48, Wl2v + (size_t)l*16*16,
                                             Wsis + (size_t)l*32*32, Wsiv + (size_t)l*16*16,
                                             harr, mixar, l, xcur, xo2, Q,
                                             Wl1s + (size_t)lN*32*32, Wl1v + (size_t)lN*16*16,
                                             s1, v1, nsb, nsb2, nvba, nvbb,
                                             (l + 1 < LL) ? 1 : 0);
        float* ts = curS; curS = oldS; oldS = ts;
        float* tv = curV; curV = oldV; oldV = tv;
    }
}

// Round 14
// 229.912 us; speedup vs baseline: 1.5410x; 1.0074x over previous
//
#include <hip/hip_runtime.h>
#include <hip/hip_bf16.h>
#include <math.h>

// Problem constants
#define NN   2048
#define EE   32768
#define NS   32
#define NV   16
#define NB   8          // NUM_BASIS
#define DD   32
#define TT   32
#define LL   2
#define HRD  64
#define NWW  3072
#define TPE  128        // edges per k_tp tile
#define PI_F 3.14159265358979323846f

// scales
#define SC_SCS (1.0f/32.0f)                 // 1/sqrt(NS*D)
#define SC_SCV 0.04419417382415922f         // 1/sqrt(NV*D)=1/sqrt(512)
#define SC_L1S 0.17677669529663687f         // 1/sqrt(32)
#define SC_L1V 0.25f                        // 1/sqrt(16)
#define SC_R1  0.25f                        // 1/sqrt(2B)
#define SC_R2  0.125f                       // 1/sqrt(HR)
#define SC_ES  0.10206207261596575f         // 1/sqrt(96)
#define SC_EV  0.125f                       // 1/sqrt(64)
#define SC_AGG 0.25f                        // 1/sqrt(16)
#define SC_L2S 0.14433756729740643f         // 1/sqrt(48)
#define SC_L2V 0.25f
#define SC_SIS 0.17677669529663687f
#define SC_SIV 0.25f

typedef __attribute__((ext_vector_type(8))) short  short8;   // 8 bf16 (4 VGPRs)
typedef __attribute__((ext_vector_type(4))) float  floatx4;  // MFMA C/D

__device__ __forceinline__ void load_lds16(const void* g, void* l) {
    __builtin_amdgcn_global_load_lds(
        (const __attribute__((address_space(1))) unsigned int*)g,
        (__attribute__((address_space(3))) unsigned int*)l, 16, 0, 0);
}

__device__ __forceinline__ floatx4 mfma16(short8 a, short8 b, floatx4 c) {
    return __builtin_amdgcn_mfma_f32_16x16x32_bf16(a, b, c, 0, 0, 0);
}

// Parallel segmented reduction over the dst-sorted 128-edge tile.
__device__ __forceinline__ void seg_reduce_store(
        const float (*red)[49], const int* dst_s,
        const int* __restrict__ row_ptr, int ebase,
        int tid, int wave, int lane,
        int* segstart_s, int* wtot_s, int* nseg_s,
        float* __restrict__ outg) {
    int seg_flag = 0, seg_lidx = 0;
    if (tid < TPE) {   // waves 0 and 1, fully active
        seg_flag = (tid == 0) || (dst_s[tid] != dst_s[tid - 1]);
        unsigned long long m = __ballot(seg_flag != 0);
        if (lane == 0) wtot_s[wave] = (int)__popcll(m);
        seg_lidx = (int)__popcll(m & ((1ull << lane) - 1ull));
    }
    __syncthreads();
    if (seg_flag) segstart_s[seg_lidx + (wave ? wtot_s[0] : 0)] = tid;
    if (tid == 0) {
        int ns = wtot_s[0] + wtot_s[1];
        nseg_s[0] = ns;
        segstart_s[ns] = TPE;   // sentinel
    }
    __syncthreads();
    int nseg = nseg_s[0];
    for (int w = tid; w < nseg * 48; w += 256) {
        int seg = w / 48, c = w - seg * 48;
        int p0 = segstart_s[seg], p1 = segstart_s[seg + 1];
        int d = dst_s[p0];
        float run = 0.f;
        for (int pos = p0; pos < p1; ++pos) run += red[pos][c];
        if (row_ptr[d] >= ebase && row_ptr[d + 1] <= ebase + TPE)
            outg[d * 48 + c] = run;          // tile owns the whole CSR row
        else
            atomicAdd(&outg[d * 48 + c], run);
    }
}

// ------------------------------------------------------------- K_setup
// block 0: QR; 1..64: per-type sc weights; 65..1600: W_r2 transform;
// 1601..1728: edge-dst HISTOGRAM (merged from k_hist -- deg/cursor are now
// zeroed by a preceding hipMemsetAsync, removing the zero->hist ordering
// dependency and one full dispatch+drain boundary).
__global__ void k_setup(const float* __restrict__ Wup, float* __restrict__ Q,
                        const float* __restrict__ emb,
                        const float* __restrict__ Wscs, const float* __restrict__ Wscv,
                        float* __restrict__ WtS, float* __restrict__ WtV,
                        const float* __restrict__ Wr2, __hip_bfloat16* __restrict__ wr2t,
                        const int* __restrict__ edst, int* __restrict__ deg) {
    int b = blockIdx.x;
    if (b == 0) {
        if (threadIdx.x != 0) return;
        double A[16][2], tau[2];
        for (int i = 0; i < 16; ++i)
            for (int j = 0; j < 2; ++j) A[i][j] = (double)Wup[i*2 + j];
        for (int j = 0; j < 2; ++j) {
            double alpha = A[j][j];
            double xn2 = 0.0;
            for (int i = j + 1; i < 16; ++i) xn2 += A[i][j]*A[i][j];
            if (xn2 == 0.0) {
                tau[j] = 0.0;
            } else {
                double nrm  = sqrt(alpha*alpha + xn2);
                double beta = (alpha >= 0.0) ? -nrm : nrm;
                tau[j] = (beta - alpha) / beta;
                double s = 1.0 / (alpha - beta);
                for (int i = j + 1; i < 16; ++i) A[i][j] *= s;
                A[j][j] = beta;
            }
            for (int k = j + 1; k < 2; ++k) {
                double w = A[j][k];
                for (int i = j + 1; i < 16; ++i) w += A[i][j]*A[i][k];
                w *= tau[j];
                A[j][k] -= w;
                for (int i = j + 1; i < 16; ++i) A[i][k] -= A[i][j]*w;
            }
        }
        double Qm[16][2];
        for (int i = 0; i < 16; ++i)
            for (int j = 0; j < 2; ++j) Qm[i][j] = (i == j) ? 1.0 : 0.0;
        for (int j = 1; j >= 0; --j) {
            for (int k = 0; k < 2; ++k) {
                double w = Qm[j][k];
                for (int i = j + 1; i < 16; ++i) w += A[i][j]*Qm[i][k];
                w *= tau[j];
                Qm[j][k] -= w;
                for (int i = j + 1; i < 16; ++i) Qm[i][k] -= A[i][j]*w;
            }
        }
        for (int i = 0; i < 16; ++i)
            for (int j = 0; j < 2; ++j) Q[i*2 + j] = (float)Qm[i][j];
    } else if (b <= 64) {
        int lt = b - 1;
        int l = lt >> 5, t = lt & 31;
        __shared__ float es[32];
        if (threadIdx.x < 32) es[threadIdx.x] = emb[t*DD + threadIdx.x];
        __syncthreads();
        const float* Ws = Wscs + (size_t)l*NS*DD*48;
        float* oS = WtS + (size_t)(l*TT + t)*NS*48;
        for (int idx = threadIdx.x; idx < NS*48; idx += 256) {
            int i = idx / 48, j = idx % 48;
            float acc = 0.f;
            for (int a = 0; a < 32; ++a) acc += es[a]*Ws[(i*DD + a)*48 + j];
            oS[idx] = acc;
        }
        const float* Wv = Wscv + (size_t)l*NV*DD*NV;
        float* oV = WtV + (size_t)(l*TT + t)*NV*NV;
        for (int idx = threadIdx.x; idx < NV*NV; idx += 256) {
            int c = idx / 16, j = idx % 16;
            float acc = 0.f;
            for (int a = 0; a < 32; ++a) acc += es[a]*Wv[(c*DD + a)*NV + j];
            oV[idx] = acc;
        }
    } else if (b <= 1600) {
        int idx = (b - 65)*256 + threadIdx.x;      // L*64*3072 total, coalesced read
        int l = idx / (HRD*NWW);
        int r = idx - l*(HRD*NWW);
        int k = r / NWW;
        int c = r - k*NWW;
        int ch = c >> 6, cc = c & 63, q = cc >> 4, tcc = cc & 15;
        int h = k >> 5, qd = (k >> 3) & 3, j = k & 7;
        size_t dst = (size_t)l*(NWW*HRD)
                   + (size_t)((ch*32 + q*8 + h*4 + qd)*128 + tcc*8 + j);
        wr2t[dst] = __float2bfloat16(Wr2[idx]);
    } else {
        int e = (b - 1601)*256 + threadIdx.x;      // exactly EE
        atomicAdd(&deg[edst[e]], 1);
    }
}

// --------------------------------------------------------------- CSR build
__global__ void k_scan(const int* __restrict__ deg, int* __restrict__ row_ptr) {
    __shared__ int wsum[4];
    int t = threadIdx.x;
    int lane = t & 63, wave = t >> 6;
    int loc[8]; int s = 0;
    for (int k = 0; k < 8; ++k) { loc[k] = deg[t*8 + k]; s += loc[k]; }
    int inc = s;
    for (int d = 1; d < 64; d <<= 1) {
        int v = __shfl_up(inc, d);
        if (lane >= d) inc += v;
    }
    if (lane == 63) wsum[wave] = inc;
    __syncthreads();
    int woff = 0;
    for (int w = 0; w < wave; ++w) woff += wsum[w];
    int off = woff + inc - s;   // exclusive prefix for this thread
    for (int k = 0; k < 8; ++k) { row_ptr[t*8 + k] = off; off += loc[k]; }
    if (t == 255) row_ptr[2048] = off;
}

// blocks 0..127: fill pre-permuted src/dst; 128..511: element-parallel init.
__global__ void k_fill(const int* __restrict__ esrc, const int* __restrict__ edst,
                       const int* __restrict__ row_ptr, int* __restrict__ cursor,
                       int* __restrict__ srcs, int* __restrict__ dsts,
                       const float* __restrict__ xin, const float* __restrict__ Q,
                       float* __restrict__ ys0, float* __restrict__ yv0,
                       float* __restrict__ ys1, float* __restrict__ yv1,
                       float* __restrict__ xcur,
                       const float* __restrict__ Wl1v0,
                       float* __restrict__ s1, float* __restrict__ v1,
                       float* __restrict__ nsb, float* __restrict__ nsb2,
                       float* __restrict__ nvba, float* __restrict__ nvbb) {
    if (blockIdx.x < 128) {
        int e = blockIdx.x*256 + threadIdx.x;
        int d = edst[e];
        int pos = atomicAdd(&cursor[d], 1);
        int p = row_ptr[d] + pos;
        srcs[p] = esrc[e];
        dsts[p] = d;
    } else {
        int idx = (blockIdx.x - 128)*256 + threadIdx.x;   // [0, NN*48)
        int n = idx / 48, r = idx - 48*(idx / 48);
        int j = r/3, k = r - 3*j;
        float xk  = xin[n*6 + k];
        float xk3 = xin[n*6 + 3 + k];
        float yvv = Q[j*2 + 0]*xk + Q[j*2 + 1]*xk3;
        yv0[idx] = yvv;
        yv1[idx] = yvv;
        float a = 0.f;
        for (int c = 0; c < 16; ++c) {
            float yc = Q[c*2 + 0]*xk + Q[c*2 + 1]*xk3;
            a += yc*Wl1v0[c*16 + j];
        }
        v1[idx] = a*SC_L1V;
        nsb[idx] = 0.f; nsb2[idx] = 0.f;
        nvba[idx] = 0.f; nvbb[idx] = 0.f;
        if (r < 32) {
            int si = n*32 + r;
            ys0[si] = 0.f; ys1[si] = 0.f; s1[si] = 0.f;
        }
        if (r < 6) xcur[n*6 + r] = xin[n*6 + r];
    }
}

// ------------------------------ K_tp: FUSED edge geometry + radial MLP +
// radial2-MFMA + edge TP + reduce (R13 verbatim -- verified 59us/231.6us).
__global__ void __launch_bounds__(256, 3) k_tp(
        const float* __restrict__ xcur,
        const int* __restrict__ srcs, const int* __restrict__ dsts,
        const int* __restrict__ row_ptr,
        const float* __restrict__ Wr1l,
        const __hip_bfloat16* __restrict__ wr2tl,
        const float* __restrict__ s1g, const float* __restrict__ v1g,
        float* __restrict__ nsb, float* __restrict__ nsb2,
        float* __restrict__ nvba, float* __restrict__ nvbb) {
    __shared__ __align__(16) char smem[41728];
    __shared__ float ea_s[TPE][9];
    __shared__ int   src_s[TPE];
    __shared__ int   dst_s[TPE];
    __shared__ int   segstart_s[TPE + 1];
    __shared__ int   wtot_s[2];
    __shared__ int   nseg_s[1];

    int bid = blockIdx.x;
    int region = bid % 3;
    int tile   = bid / 3;
    int ebase  = tile*TPE;
    int tid = threadIdx.x;
    int wave = tid >> 6, lane = tid & 63;
    int tc = tid & 15;
    int quad = lane >> 4;

    float* ef_lds  = (float*)smem;                       // [16][132]
    float* Wr1_lds = (float*)(smem + 8448);              // [1024]
    __hip_bfloat16* hr_lds = (__hip_bfloat16*)(smem + 12544);  // [128][72]

    if (tid < TPE) { src_s[tid] = srcs[ebase + tid]; dst_s[tid] = dsts[ebase + tid]; }
    for (int i = tid; i < 16*64; i += 256) Wr1_lds[i] = Wr1l[i];

    // ---- geometry: thread e = tid < 128
    if (tid < TPE) {
        int s = src_s[tid], d = dst_s[tid];
        for (int m = 0; m < 2; ++m) {
            float v0 = xcur[s*6 + m*3 + 0] - xcur[d*6 + m*3 + 0];
            float v1_ = xcur[s*6 + m*3 + 1] - xcur[d*6 + m*3 + 1];
            float v2 = xcur[s*6 + m*3 + 2] - xcur[d*6 + m*3 + 2];
            float len = sqrtf(v0*v0 + v1_*v1_ + v2*v2 + 1e-12f);
            float inv = 1.0f/len;
            float theta = len*(PI_F/3.0f);
            float s1v = sinf(theta), c1v = cosf(theta);
            float sc  = 2.3094010767585034f*inv;  // sqrt(2/3)*sqrt(8)
            float sp = 0.f, scur = s1v, twoc = 2.f*c1v;
            for (int bq = 0; bq < 8; ++bq) {
                ef_lds[(m*8 + bq)*132 + tid] = sc*scur;
                float sn = twoc*scur - sp;
                sp = scur; scur = sn;
            }
            float u = 2.0f*(len*(1.0f/3.0f) - 1.0f);
            float cut;
            if (u > 0.f) cut = 0.f;
            else if (u < -1.f) cut = 1.f;
            else cut = 0.5f*(1.0f - cosf(PI_F*u));
            float shs = 1.7320508075688772f*inv*cut;
            ea_s[tid][m*3 + 0] = shs*v0;
            ea_s[tid][m*3 + 1] = shs*v1_;
            ea_s[tid][m*3 + 2] = shs*v2;
        }
    }
    __syncthreads();

    // ---- radial MLP: e = tid>>1, half h = tid&1 (32 outs each)
    {
        int e = tid >> 1, h = tid & 1;
        float z[32];
        #pragma unroll
        for (int k = 0; k < 32; ++k) z[k] = 0.f;
        for (int f = 0; f < 16; ++f) {
            float efv = ef_lds[f*132 + e];
            #pragma unroll
            for (int k = 0; k < 32; ++k) z[k] += efv*Wr1_lds[f*64 + h*32 + k];
        }
        #pragma unroll
        for (int q8 = 0; q8 < 4; ++q8) {
            __hip_bfloat16 tmp[8];
            #pragma unroll
            for (int j = 0; j < 8; ++j) {
                float zz = z[q8*8 + j]*SC_R1;
                tmp[j] = __float2bfloat16(zz/(1.0f + expf(-zz)));
            }
            *(short8*)&hr_lds[e*72 + h*32 + q8*8] = *(short8*)tmp;
        }
    }
    __syncthreads();

    // ---- A fragments from hr_lds: 2 row-tiles per wave
    const short* hrp = (const short*)(smem + 12544);
    short8 a_lo[2], a_hi[2];
    #pragma unroll
    for (int rt = 0; rt < 2; ++rt) {
        int row = (wave*2 + rt)*16 + tc;
        a_lo[rt] = *(const short8*)(hrp + row*72 + quad*8);
        a_hi[rt] = *(const short8*)(hrp + row*72 + 32 + quad*8);
    }
    __syncthreads();   // hr/ef/Wr1 dead; smem reusable for gathers

    const char* wb = (const char*)wr2tl;   // staging layout: chunk ch at ch*8192
    const float sES = SC_R2*SC_ES*SC_AGG;
    const float sEV = SC_R2*SC_EV*SC_AGG;

    char* Bbuf;
    if (region == 0)      Bbuf = smem + 16896;
    else if (region == 1) Bbuf = smem + 16896;
    else                  Bbuf = smem + 25344;

    auto stage = [&](int ch, int b) {
        const char* g = wb + (size_t)ch*8192 + wave*2048 + lane*16;
        char* l = Bbuf + b*8192 + wave*2048;       // wave-uniform lds base
        load_lds16(g, l);
        load_lds16(g + 1024, l + 1024);
    };

    if (region == 0) {
        // ---------------- sv: ch 0..15 -> accF (ea-factored) -> nvb_a
        float (*s1t)[132] = (float(*)[132])smem;            // 16896 B
        for (int i = tid; i < TPE*32; i += 256) {
            int e = i >> 5, s = i & 31;
            s1t[s][e] = s1g[src_s[e]*32 + s];
        }
        stage(0, 0);

        float accF[2][4][2] = {};
        for (int ci = 0; ci < 16; ++ci) {
            __syncthreads();                       // drains stage(ci) + gather
            if (ci + 1 < 16) stage(ci + 1, (ci + 1) & 1);
            const char* B = Bbuf + (ci & 1)*8192;
            #pragma unroll
            for (int q = 0; q < 4; ++q) {
                short8 b_lo = *(const short8*)(B + (q*8 + quad)*256 + tc*16);
                short8 b_hi = *(const short8*)(B + (q*8 + 4 + quad)*256 + tc*16);
                floatx4 c0 = {0.f,0.f,0.f,0.f}, c1 = {0.f,0.f,0.f,0.f};
                c0 = mfma16(a_lo[0], b_lo, c0); c0 = mfma16(a_hi[0], b_hi, c0);
                c1 = mfma16(a_lo[1], b_lo, c1); c1 = mfma16(a_hi[1], b_hi, c1);
                int m = q & 1;
                int sidx = ci*2 + (q >> 1);
                #pragma unroll
                for (int rt = 0; rt < 2; ++rt) {
                    int e0r = (wave*2 + rt)*16 + quad*4;
                    float4 sv = *(const float4*)&s1t[sidx][e0r];
                    floatx4 cc = rt ? c1 : c0;
                    #pragma unroll
                    for (int i = 0; i < 4; ++i)
                        accF[rt][i][m] += cc[i]*((&sv.x)[i]);
                }
            }
        }
        __syncthreads();
        float (*red)[49] = (float(*)[49])smem;
        #pragma unroll
        for (int rt = 0; rt < 2; ++rt) {
            int e0r = (wave*2 + rt)*16 + quad*4;
            #pragma unroll
            for (int i = 0; i < 4; ++i) {
                int pos = e0r + i;
                float f0 = accF[rt][i][0]*sEV, f1 = accF[rt][i][1]*sEV;
                #pragma unroll
                for (int k = 0; k < 3; ++k)
                    red[pos][tc*3 + k] = f0*ea_s[pos][k] + f1*ea_s[pos][3 + k];
            }
        }
        __syncthreads();
        seg_reduce_store((const float(*)[49])smem, dst_s, row_ptr, ebase,
                         tid, wave, lane, segstart_s, wtot_s, nseg_s, nvba);
    } else if (region == 1) {
        // ---------------- vs part 1: ch 16..31 -> accES -> nsb
        float (*dots_t)[132] = (float(*)[132])smem;           // 16896 B
        float (*v1h)[132]    = (float(*)[132])(smem + 16896); // 24 rows, dies
        for (int half = 0; half < 2; ++half) {
            int jbase = half*24;
            for (int i = tid; i < TPE*24; i += 256) {
                int e = i/24, j = i - 24*(i/24);
                v1h[j][e] = v1g[src_s[e]*48 + jbase + j];
            }
            __syncthreads();
            for (int i = tid; i < TPE*16; i += 256) {
                int cm = i >> 7, e = i & (TPE - 1);
                int c = cm >> 1, m = cm & 1;
                dots_t[half*16 + cm][e] = v1h[c*3+0][e]*ea_s[e][m*3+0]
                                        + v1h[c*3+1][e]*ea_s[e][m*3+1]
                                        + v1h[c*3+2][e]*ea_s[e][m*3+2];
            }
            __syncthreads();   // v1h dead after last half; Bbuf may overwrite
        }
        stage(16, 0);

        float accES[2][4][3] = {};
        for (int ci = 16; ci < 32; ++ci) {
            __syncthreads();
            if (ci + 1 < 32) stage(ci + 1, (ci + 1) & 1);
            const char* B = Bbuf + (ci & 1)*8192;
            #pragma unroll
            for (int q = 0; q < 4; ++q) {
                short8 b_lo = *(const short8*)(B + (q*8 + quad)*256 + tc*16);
                short8 b_hi = *(const short8*)(B + (q*8 + 4 + quad)*256 + tc*16);
                floatx4 c0 = {0.f,0.f,0.f,0.f}, c1 = {0.f,0.f,0.f,0.f};
                c0 = mfma16(a_lo[0], b_lo, c0); c0 = mfma16(a_hi[0], b_hi, c0);
                c1 = mfma16(a_lo[1], b_lo, c1); c1 = mfma16(a_hi[1], b_hi, c1);
                int u = ci*4 + q - 64;           // [0,64)
                int c = (u*10923) >> 16;         // u/6
                int v6 = u - 6*c;
                int m = (v6 >= 3) ? 1 : 0;
                int g = v6 - 3*m;
                #pragma unroll
                for (int rt = 0; rt < 2; ++rt) {
                    int e0r = (wave*2 + rt)*16 + quad*4;
                    float4 dv = *(const float4*)&dots_t[c*2 + m][e0r];
                    floatx4 cc = rt ? c1 : c0;
                    #pragma unroll
                    for (int i = 0; i < 4; ++i)
                        accES[rt][i][g] += cc[i]*((&dv.x)[i]);
                }
            }
        }
        __syncthreads();
        float (*red)[49] = (float(*)[49])smem;
        #pragma unroll
        for (int rt = 0; rt < 2; ++rt) {
            int e0r = (wave*2 + rt)*16 + quad*4;
            #pragma unroll
            for (int i = 0; i < 4; ++i) {
                int pos = e0r + i;
                red[pos][tc]      = accES[rt][i][0]*sES;
                red[pos][16 + tc] = accES[rt][i][1]*sES;
                red[pos][32 + tc] = accES[rt][i][2]*sES;
            }
        }
        __syncthreads();
        seg_reduce_store((const float(*)[49])smem, dst_s, row_ptr, ebase,
                         tid, wave, lane, segstart_s, wtot_s, nseg_s, nsb);
    } else {
        // ------- vs part 2 (ch 32..39, in-loop ea dot -> nsb2)
        //         + vv (ch 40..47, ea-factored accV -> cross -> nvbb)
        float (*v1t)[132] = (float(*)[132])smem;              // 25344 B
        for (int i = tid; i < TPE*48; i += 256) {
            int e = i/48, j = i%48;
            v1t[j][e] = v1g[src_s[e]*48 + j];
        }
        stage(32, 0);   // Bbuf at 25344, disjoint from v1t

        float accES[2][4][3] = {};
        float accV[2][4][2][3] = {};
        for (int ci = 32; ci < 48; ++ci) {
            __syncthreads();
            if (ci + 1 < 48) stage(ci + 1, (ci + 1) & 1);
            const char* B = Bbuf + (ci & 1)*8192;
            #pragma unroll
            for (int q = 0; q < 4; ++q) {
                short8 b_lo = *(const short8*)(B + (q*8 + quad)*256 + tc*16);
                short8 b_hi = *(const short8*)(B + (q*8 + 4 + quad)*256 + tc*16);
                floatx4 c0 = {0.f,0.f,0.f,0.f}, c1 = {0.f,0.f,0.f,0.f};
                c0 = mfma16(a_lo[0], b_lo, c0); c0 = mfma16(a_hi[0], b_hi, c0);
                c1 = mfma16(a_lo[1], b_lo, c1); c1 = mfma16(a_hi[1], b_hi, c1);
                if (ci < 40) {
                    int u = ci*4 + q - 64;           // [64,96)
                    int c = (u*10923) >> 16;         // u/6
                    int v6 = u - 6*c;
                    int m = (v6 >= 3) ? 1 : 0;
                    int g = v6 - 3*m;
                    #pragma unroll
                    for (int rt = 0; rt < 2; ++rt) {
                        int e0r = (wave*2 + rt)*16 + quad*4;
                        float4 vx = *(const float4*)&v1t[c*3 + 0][e0r];
                        float4 vy = *(const float4*)&v1t[c*3 + 1][e0r];
                        float4 vz = *(const float4*)&v1t[c*3 + 2][e0r];
                        floatx4 cc = rt ? c1 : c0;
                        #pragma unroll
                        for (int i = 0; i < 4; ++i) {
                            float dot = (&vx.x)[i]*ea_s[e0r + i][m*3 + 0]
                                      + (&vy.x)[i]*ea_s[e0r + i][m*3 + 1]
                                      + (&vz.x)[i]*ea_s[e0r + i][m*3 + 2];
                            accES[rt][i][g] += cc[i]*dot;
                        }
                    }
                } else {
                    int c = ci*2 - 80 + (q >> 1);
                    int m = q & 1;
                    #pragma unroll
                    for (int rt = 0; rt < 2; ++rt) {
                        int e0r = (wave*2 + rt)*16 + quad*4;
                        float4 vx = *(const float4*)&v1t[c*3 + 0][e0r];
                        float4 vy = *(const float4*)&v1t[c*3 + 1][e0r];
                        float4 vz = *(const float4*)&v1t[c*3 + 2][e0r];
                        floatx4 cc = rt ? c1 : c0;
                        #pragma unroll
                        for (int i = 0; i < 4; ++i) {
                            float ww = cc[i];
                            accV[rt][i][m][0] += ww*((&vx.x)[i]);
                            accV[rt][i][m][1] += ww*((&vy.x)[i]);
                            accV[rt][i][m][2] += ww*((&vz.x)[i]);
                        }
                    }
                }
            }
        }
        // epilogue 1: accES -> nsb2
        __syncthreads();           // v1t dead; red may overwrite
        float (*red)[49] = (float(*)[49])smem;
        #pragma unroll
        for (int rt = 0; rt < 2; ++rt) {
            int e0r = (wave*2 + rt)*16 + quad*4;
            #pragma unroll
            for (int i = 0; i < 4; ++i) {
                int pos = e0r + i;
                red[pos][tc]      = accES[rt][i][0]*sES;
                red[pos][16 + tc] = accES[rt][i][1]*sES;
                red[pos][32 + tc] = accES[rt][i][2]*sES;
            }
        }
        __syncthreads();
        seg_reduce_store((const float(*)[49])smem, dst_s, row_ptr, ebase,
                         tid, wave, lane, segstart_s, wtot_s, nseg_s, nsb2);
        // epilogue 2: accV x ea (cross products) -> nvbb
        __syncthreads();           // all done reading red from epilogue 1
        #pragma unroll
        for (int rt = 0; rt < 2; ++rt) {
            int e0r = (wave*2 + rt)*16 + quad*4;
            #pragma unroll
            for (int i = 0; i < 4; ++i) {
                int pos = e0r + i;
                float u00 = accV[rt][i][0][0], u01 = accV[rt][i][0][1], u02 = accV[rt][i][0][2];
                float u10 = accV[rt][i][1][0], u11 = accV[rt][i][1][1], u12 = accV[rt][i][1][2];
                float a0 = ea_s[pos][0], a1 = ea_s[pos][1], a2 = ea_s[pos][2];
                float b0 = ea_s[pos][3], b1 = ea_s[pos][4], b2 = ea_s[pos][5];
                red[pos][tc*3 + 0] = (u01*a2 - u02*a1 + u11*b2 - u12*b1)*sEV;
                red[pos][tc*3 + 1] = (u02*a0 - u00*a2 + u12*b0 - u10*b2)*sEV;
                red[pos][tc*3 + 2] = (u00*a1 - u01*a0 + u10*b1 - u11*b0)*sEV;
            }
        }
        __syncthreads();
        seg_reduce_store((const float(*)[49])smem, dst_s, row_ptr, ebase,
                         tid, wave, lane, segstart_s, wtot_s, nseg_s, nvbb);
    }
}

// ----------------------- K6: node update (conv, gate, si, leapfrog, project)
// + FUSED next-layer lin1 + aggregator zeroing for the next k_tp.
__global__ void __launch_bounds__(256) k_nodepost(
        const float* __restrict__ ysC, const float* __restrict__ yvC,
        float* __restrict__ ysO, float* __restrict__ yvO,
        const float* __restrict__ nsb, const float* __restrict__ nsb2,
        const float* __restrict__ nvba, const float* __restrict__ nvbb,
        const int* __restrict__ nattr,
        const float* __restrict__ WtSl, const float* __restrict__ WtVl,
        const float* __restrict__ Wl2s, const float* __restrict__ Wl2v,
        const float* __restrict__ Wsis, const float* __restrict__ Wsiv,
        const float* __restrict__ harr, const float* __restrict__ mixarr, int l,
        float* __restrict__ xcur, float* __restrict__ xout2,
        const float* __restrict__ Qg,
        const float* __restrict__ Wl1sN, const float* __restrict__ Wl1vN,
        float* __restrict__ s1, float* __restrict__ v1,
        float* __restrict__ znsb, float* __restrict__ znsb2,
        float* __restrict__ znvba, float* __restrict__ znvbb,
        int do_next) {
    int wave = threadIdx.x >> 6, lane = threadIdx.x & 63;
    int n = blockIdx.x*4 + wave;
    __shared__ float ys_s[4][32], yv_s[4][48], ns_s[4][48], nv_s[4][48];
    __shared__ float cs_s[4][48], nvo_s[4][48], nsn_s[4][32];

    if (lane < 32) ys_s[wave][lane] = ysC[n*32 + lane];
    if (lane < 48) {
        yv_s[wave][lane] = yvC[n*48 + lane];
        ns_s[wave][lane] = nsb[n*48 + lane] + nsb2[n*48 + lane];
        nv_s[wave][lane] = nvba[n*48 + lane] + nvbb[n*48 + lane];
    }
    __syncthreads();
    int t = nattr[n];
    const float* WtSn = WtSl + (size_t)t*NS*48;
    const float* WtVn = WtVl + (size_t)t*NV*NV;
    float hv = harr[l];
    float h2 = hv*hv, mx = mixarr[l];

    if (lane < 48) {
        float sc = 0.f, s2 = 0.f;
        for (int i = 0; i < 32; ++i) sc += ys_s[wave][i]*WtSn[i*48 + lane];
        for (int c = 0; c < 48; ++c) s2 += ns_s[wave][c]*Wl2s[c*48 + lane];
        cs_s[wave][lane] = sc*SC_SCS + s2*SC_L2S;
    }
    __syncthreads();
    if (lane < 48) {
        int j = lane/3, k = lane - 3*j;
        float scv = 0.f, v2 = 0.f, siv = 0.f;
        for (int c = 0; c < 16; ++c) {
            float yvv = yv_s[wave][c*3 + k];
            scv += yvv*WtVn[c*16 + j];
            v2  += nv_s[wave][c*3 + k]*Wl2v[c*16 + j];
            siv += yvv*Wsiv[c*16 + j];
        }
        float convv = scv*SC_SCV + v2*SC_L2V;
        siv *= SC_SIV;
        float gate = 1.f/(1.f + expf(-cs_s[wave][32 + j]));
        float gv = gate*convv;
        float nvnew = 2.f*yv_s[wave][lane] - yvO[n*48 + lane] + h2*(mx*gv + (mx - 1.f)*siv);
        nvo_s[wave][lane] = nvnew;
        yvO[n*48 + lane] = nvnew;
    }
    if (lane < 32) {
        float sis = 0.f;
        for (int i = 0; i < 32; ++i) sis += ys_s[wave][i]*Wsis[i*32 + lane];
        sis *= SC_SIS;
        float cs = cs_s[wave][lane];
        float gs = cs/(1.f + expf(-cs));
        float nsnew = 2.f*ys_s[wave][lane] - ysO[n*32 + lane] + h2*(mx*gs + (mx - 1.f)*sis);
        nsn_s[wave][lane] = nsnew;
        ysO[n*32 + lane] = nsnew;
    }
    __syncthreads();
    if (lane < 6) {
        int i = lane/3, k = lane - 3*(lane/3);
        float acc = 0.f;
        for (int c = 0; c < 16; ++c) acc += Qg[c*2 + i]*nvo_s[wave][c*3 + k];
        xcur[n*6 + lane]  = acc;
        xout2[n*6 + lane] = acc;
    }
    if (do_next) {
        if (lane < 32) {
            float a = 0.f;
            for (int i = 0; i < 32; ++i) a += nsn_s[wave][i]*Wl1sN[i*32 + lane];
            s1[n*32 + lane] = a*SC_L1S;
        }
        if (lane < 48) {
            int j = lane/3, k = lane - 3*j;
            float a = 0.f;
            for (int c = 0; c < 16; ++c) a += nvo_s[wave][c*3 + k]*Wl1vN[c*16 + j];
            v1[n*48 + lane] = a*SC_L1V;
            znsb[n*48 + lane] = 0.f; znsb2[n*48 + lane] = 0.f;
            znvba[n*48 + lane] = 0.f; znvbb[n*48 + lane] = 0.f;
        }
    }
}

// ---------------------------------------------------------------- launch
extern "C" void kernel_launch(void* const* d_in, const int* in_sizes, int n_in,
                              void* d_out, int out_size, void* d_ws, size_t ws_size,
                              hipStream_t stream) {
    const float* x_in  = (const float*)d_in[0];
    const int*   nattr = (const int*)  d_in[2];
    const int*   esrc  = (const int*)  d_in[3];
    const int*   edst  = (const int*)  d_in[4];
    const float* emb   = (const float*)d_in[5];
    const float* Wup   = (const float*)d_in[6];
    const float* Wscs  = (const float*)d_in[7];
    const float* Wscv  = (const float*)d_in[8];
    const float* Wl1s  = (const float*)d_in[9];
    const float* Wl1v  = (const float*)d_in[10];
    const float* Wr1   = (const float*)d_in[11];
    const float* Wr2   = (const float*)d_in[12];
    const float* Wl2s  = (const float*)d_in[13];
    const float* Wl2v  = (const float*)d_in[14];
    const float* Wsis  = (const float*)d_in[15];
    const float* Wsiv  = (const float*)d_in[16];
    const float* harr  = (const float*)d_in[17];
    const float* mixar = (const float*)d_in[18];
    float* out = (float*)d_out;

    float* ws = (float*)d_ws;
    size_t off = 0;
    float* Q    = ws + off; off += 32;
    float* WtS  = ws + off; off += (size_t)LL*TT*NS*48;     // 98304
    float* WtV  = ws + off; off += (size_t)LL*TT*NV*NV;     // 16384
    float* ys0  = ws + off; off += (size_t)NN*32;
    float* yv0  = ws + off; off += (size_t)NN*48;
    float* ys1  = ws + off; off += (size_t)NN*32;
    float* yv1  = ws + off; off += (size_t)NN*48;
    float* xcur = ws + off; off += (size_t)NN*6;
    float* s1   = ws + off; off += (size_t)NN*32;
    float* v1   = ws + off; off += (size_t)NN*48;
    float* nsb  = ws + off; off += (size_t)NN*48;
    float* nsb2 = ws + off; off += (size_t)NN*48;
    float* nvba = ws + off; off += (size_t)NN*48;
    float* nvbb = ws + off; off += (size_t)NN*48;
    off = (off + 3) & ~(size_t)3;                           // 16B align
    __hip_bfloat16* wr2t = (__hip_bfloat16*)(ws + off); off += (size_t)LL*NWW*HRD/2;  // bf16
    int* deg     = (int*)(ws + off); off += NN;
    int* cursor  = (int*)(ws + off); off += NN;
    int* row_ptr = (int*)(ws + off); off += NN + 1;
    int* srcs    = (int*)(ws + off); off += EE;
    int* dsts    = (int*)(ws + off); off += EE;

    // zero deg+cursor (contiguous) via async memset -- removes the
    // zero->hist ordering dependency so hist merges into k_setup.
    hipMemsetAsync(deg, 0, (size_t)2*NN*sizeof(int), stream);

    k_setup<<<1729, 256, 0, stream>>>(Wup, Q, emb, Wscs, Wscv, WtS, WtV, Wr2, wr2t,
                                      edst, deg);
    k_scan<<<1, 256, 0, stream>>>(deg, row_ptr);
    k_fill<<<128 + NN*48/256, 256, 0, stream>>>(esrc, edst, row_ptr, cursor, srcs, dsts,
                                    x_in, Q, ys0, yv0, ys1, yv1, xcur,
                                    Wl1v, s1, v1, nsb, nsb2, nvba, nvbb);

    float* curS = ys0; float* curV = yv0;
    float* oldS = ys1; float* oldV = yv1;
    for (int l = 0; l < LL; ++l) {
        k_tp<<<3*EE/TPE, 256, 0, stream>>>(xcur, srcs, dsts, row_ptr,
                                           Wr1 + (size_t)l*16*64,
                                           wr2t + (size_t)l*NWW*HRD,
                                           s1, v1, nsb, nsb2, nvba, nvbb);
        float* xo2 = (l == LL - 1) ? out : xcur;
        int lN = (l + 1 < LL) ? (l + 1) : l;
        k_nodepost<<<NN/4, 256, 0, stream>>>(curS, curV, oldS, oldV,
                                             nsb, nsb2, nvba, nvbb, nattr,
                                             WtS + (size_t)l*TT*NS*48, WtV + (size_t)l*TT*NV*NV,
                                             Wl2s + (size_t)l*48*48, Wl2v + (size_t)l*16*16,
                                             Wsis + (size_t)l*32*32, Wsiv + (size_t)l*16*16,
                                             harr, mixar, l, xcur, xo2, Q,
                                             Wl1s + (size_t)lN*32*32, Wl1v + (size_t)lN*16*16,
                                             s1, v1, nsb, nsb2, nvba, nvbb,
                                             (l + 1 < LL) ? 1 : 0);
        float* ts = curS; curS = oldS; oldS = ts;
        float* tv = curV; curV = oldV; oldV = tv;
    }
}